// Round 8
// baseline (1380.689 us; speedup 1.0000x reference)
//
#include <hip/hip_runtime.h>

#define DEVINL static __device__ __forceinline__

namespace {

typedef __attribute__((ext_vector_type(8))) short bf16x8;
typedef __attribute__((ext_vector_type(4))) float f32x4;

constexpr int NV = 100000;   // variables
constexpr int NC = 50000;    // constraints
constexpr int NK = 20000;    // cuts
constexpr int EVC = 800000;  // var-cons edges
constexpr int EVK = 200000;  // var-cut edges
constexpr int E_TOT2 = 2 * (EVC + EVK);  // 2M staged entries
constexpr int R_TOT = NC + NV + NK + NV;  // 270000 CSR rows
constexpr int SCAN_CHUNK = 2048;
constexpr int SCAN_NB = (R_TOT + SCAN_CHUNK - 1) / SCAN_CHUNK;  // 132
constexpr int PACK_PER_LAYER = 28672;  // ushort per layer of packed MP weights
constexpr float WQ_SCALE = 16383.0f;
constexpr float WQ_INV = 1.0f / 16383.0f;

// ---- atomic-free CSR fill: 8 row-range bins, XCD-pinned (blockIdx&7) ----
__constant__ int c_bin_hi[8] = {12500, 25000, 37500, 50000,
                                83334, 116667, 150000, 270000};
__constant__ int c_seg_lo[8] = {0, 0, 0, 0, EVC, EVC, EVC, 2 * EVC};
__constant__ int c_seg_hi[8] = {EVC, EVC, EVC, EVC,
                                2 * EVC, 2 * EVC, 2 * EVC, E_TOT2};

// packed embedding/edge-weight matrix offsets (ushort)
constexpr int PE_VAR_W1 = 0;      // Kpad=32 -> 2048
constexpr int PE_VAR_W2 = 2048;   // K=64   -> 4096
constexpr int PE_CONS_W1 = 6144;  // 2048
constexpr int PE_CONS_W2 = 8192;  // 4096
constexpr int PE_CUT_W1 = 12288;  // 2048
constexpr int PE_CUT_W2 = 14336;  // 4096
constexpr int PE_EWVC_A = 18432;  // 4096
constexpr int PE_EWVC_B = 22528;  // 4096
constexpr int PE_EWVK_A = 26624;  // 4096
constexpr int PE_EWVK_B = 30720;  // 4096
constexpr int PE_TOTAL = 34816;

DEVINL unsigned short f2bf(float f) {
  unsigned u = __float_as_uint(f);
  u = u + 0x7fffu + ((u >> 16) & 1u);  // RNE
  return (unsigned short)(u >> 16);
}
DEVINL float bf2f(unsigned short h) {
  return __uint_as_float((unsigned)h << 16);
}

DEVINL float sigmoid_f(float x) { return 1.0f / (1.0f + __expf(-x)); }

DEVINL int row_group(int r) {
  return (r < NC) ? 0 : (r < NC + NV) ? 1 : (r < NC + NV + NK) ? 2 : 3;
}
__constant__ int c_grp_base[4] = {0, NC, NC + NV, NC + NV + NK};

// ======================= weight packing (bf16 B-frag streams) ================
DEVINL void pack_mat(const float* __restrict__ src, int K, int Kpad,
                     unsigned short* __restrict__ dst, int tid) {
  const int ntup = (Kpad / 32) * 256;
  for (int tup = tid; tup < ntup; tup += 256) {
    const int lane = tup & 63;
    const int t = (tup >> 6) & 3;
    const int kb = tup >> 8;
    const int c = t * 16 + (lane & 15);
    const int k0 = kb * 32 + (lane >> 4) * 8;
#pragma unroll
    for (int jj = 0; jj < 8; ++jj)
      dst[tup * 8 + jj] =
          (k0 + jj < K) ? f2bf(src[(k0 + jj) * 64 + c]) : (unsigned short)0;
  }
}

__global__ void __launch_bounds__(256) pack_k(
    const float* __restrict__ mW1, const float* __restrict__ mW2,
    const float* __restrict__ gW, const float* __restrict__ uW1,
    const float* __restrict__ uW2, unsigned short* __restrict__ PW) {
  const int layer = blockIdx.x;  // 0..14
  unsigned short* out = PW + (size_t)layer * PACK_PER_LAYER;
  pack_mat(mW1 + (size_t)layer * 4096, 64, 64, out, threadIdx.x);
  pack_mat(mW2 + (size_t)layer * 4096, 64, 64, out + 4096, threadIdx.x);
  pack_mat(gW + (size_t)layer * 8192, 128, 128, out + 8192, threadIdx.x);
  pack_mat(uW1 + (size_t)layer * 8192, 128, 128, out + 16384, threadIdx.x);
  pack_mat(uW2 + (size_t)layer * 4096, 64, 64, out + 24576, threadIdx.x);
}

__global__ void __launch_bounds__(256) pack_emb_k(
    const float* __restrict__ var_w1, const float* __restrict__ var_w2,
    const float* __restrict__ cons_w1, const float* __restrict__ cons_w2,
    const float* __restrict__ cut_w1, const float* __restrict__ cut_w2,
    const float* __restrict__ ewvc_w1, const float* __restrict__ ewvk_w1,
    unsigned short* __restrict__ P) {
  switch (blockIdx.x) {
    case 0: pack_mat(var_w1, 19, 32, P + PE_VAR_W1, threadIdx.x); break;
    case 1: pack_mat(var_w2, 64, 64, P + PE_VAR_W2, threadIdx.x); break;
    case 2: pack_mat(cons_w1, 5, 32, P + PE_CONS_W1, threadIdx.x); break;
    case 3: pack_mat(cons_w2, 64, 64, P + PE_CONS_W2, threadIdx.x); break;
    case 4: pack_mat(cut_w1, 30, 32, P + PE_CUT_W1, threadIdx.x); break;
    case 5: pack_mat(cut_w2, 64, 64, P + PE_CUT_W2, threadIdx.x); break;
    case 6: pack_mat(ewvc_w1, 64, 64, P + PE_EWVC_A, threadIdx.x); break;
    case 7: pack_mat(ewvc_w1 + 64 * 64, 64, 64, P + PE_EWVC_B, threadIdx.x); break;
    case 8: pack_mat(ewvk_w1, 64, 64, P + PE_EWVK_A, threadIdx.x); break;
    case 9: pack_mat(ewvk_w1 + 64 * 64, 64, 64, P + PE_EWVK_B, threadIdx.x); break;
  }
}

// ======================= embedding MLP (MFMA, K1 padded to 32) ===============
template <int DIN>
__global__ void __launch_bounds__(256) emb_mfma_k(
    const float* __restrict__ X, const unsigned short* __restrict__ W1p_,
    const unsigned short* __restrict__ W2p_, const float* __restrict__ B1,
    const float* __restrict__ B2, unsigned short* __restrict__ OUTb, int N) {
  __shared__ unsigned short lds[4][16 * 72];
  const int wave = threadIdx.x >> 6, l = threadIdx.x & 63;
  const int col = l & 15, quad = l >> 4;
  const int n0_raw = blockIdx.x * 64 + wave * 16;
  const bool dead = n0_raw >= N;
  const int n0 = dead ? 0 : n0_raw;

  bf16x8 a0;
#pragma unroll
  for (int j = 0; j < 8; ++j) {
    const int k = quad * 8 + j;
    a0[j] = (k < DIN) ? (short)f2bf(X[(size_t)(n0 + col) * DIN + k]) : (short)0;
  }
  const bf16x8* W1p = (const bf16x8*)W1p_;
  const bf16x8* W2p = (const bf16x8*)W2p_;
  f32x4 acc[4];
#pragma unroll
  for (int t = 0; t < 4; ++t) {
    const float b = B1[col + 16 * t];
    acc[t] = f32x4{b, b, b, b};
  }
#pragma unroll
  for (int t = 0; t < 4; ++t)
    acc[t] = __builtin_amdgcn_mfma_f32_16x16x32_bf16(a0, W1p[t * 64 + l], acc[t], 0, 0, 0);
  unsigned short* ld = lds[wave];
#pragma unroll
  for (int t = 0; t < 4; ++t)
#pragma unroll
    for (int r = 0; r < 4; ++r)
      ld[(quad * 4 + r) * 72 + col + 16 * t] = f2bf(fmaxf(acc[t][r], 0.0f));
  __syncthreads();
  const bf16x8 h0 = *(const bf16x8*)&ld[col * 72 + quad * 8];
  const bf16x8 h1 = *(const bf16x8*)&ld[col * 72 + 32 + quad * 8];
  f32x4 o[4];
#pragma unroll
  for (int t = 0; t < 4; ++t) {
    const float b = B2[col + 16 * t];
    o[t] = f32x4{b, b, b, b};
  }
#pragma unroll
  for (int t = 0; t < 4; ++t) {
    o[t] = __builtin_amdgcn_mfma_f32_16x16x32_bf16(h0, W2p[t * 64 + l], o[t], 0, 0, 0);
    o[t] = __builtin_amdgcn_mfma_f32_16x16x32_bf16(h1, W2p[(4 + t) * 64 + l], o[t], 0, 0, 0);
  }
  __syncthreads();
#pragma unroll
  for (int t = 0; t < 4; ++t)
#pragma unroll
    for (int r = 0; r < 4; ++r)
      ld[(quad * 4 + r) * 72 + col + 16 * t] = f2bf(o[t][r]);
  __syncthreads();
  if (!dead) {
#pragma unroll
    for (int cc = 0; cc < 2; ++cc) {
      const bf16x8 v = *(const bf16x8*)&ld[col * 72 + (quad * 2 + cc) * 8];
      *(bf16x8*)(OUTb + (size_t)(n0 + col) * 64 + (quad * 2 + cc) * 8) = v;
    }
  }
}

// ======= edge-weight per-node GEMV (MFMA); NOUT=2 shares the A-frag =========
template <int NOUT>
__global__ void __launch_bounds__(256) gemv_mfma_k(
    const unsigned short* __restrict__ Xb, const unsigned short* __restrict__ WpA_,
    const unsigned short* __restrict__ WpB_, const float* __restrict__ Bias,
    unsigned short* __restrict__ OUT0, unsigned short* __restrict__ OUT1, int N) {
  __shared__ unsigned short lds[4][16 * 72];
  const int wave = threadIdx.x >> 6, l = threadIdx.x & 63;
  const int col = l & 15, quad = l >> 4;
  const int n0_raw = blockIdx.x * 64 + wave * 16;
  const bool dead = n0_raw >= N;
  const int n0 = dead ? 0 : n0_raw;
  const unsigned short* xrow = Xb + (size_t)(n0 + col) * 64 + quad * 8;
  const bf16x8 a0 = *(const bf16x8*)xrow;
  const bf16x8 a1 = *(const bf16x8*)(xrow + 32);
  unsigned short* ld = lds[wave];
#pragma unroll
  for (int m = 0; m < NOUT; ++m) {
    const bf16x8* Wp = (const bf16x8*)(m == 0 ? WpA_ : WpB_);
    unsigned short* OUT = (m == 0) ? OUT0 : OUT1;
    f32x4 acc[4];
#pragma unroll
    for (int t = 0; t < 4; ++t) {
      const float b = (Bias != nullptr) ? Bias[col + 16 * t] : 0.0f;
      acc[t] = f32x4{b, b, b, b};
    }
#pragma unroll
    for (int t = 0; t < 4; ++t) {
      acc[t] = __builtin_amdgcn_mfma_f32_16x16x32_bf16(a0, Wp[t * 64 + l], acc[t], 0, 0, 0);
      acc[t] = __builtin_amdgcn_mfma_f32_16x16x32_bf16(a1, Wp[(4 + t) * 64 + l], acc[t], 0, 0, 0);
    }
    if (m > 0) __syncthreads();
#pragma unroll
    for (int t = 0; t < 4; ++t)
#pragma unroll
      for (int r = 0; r < 4; ++r)
        ld[(quad * 4 + r) * 72 + col + 16 * t] = f2bf(acc[t][r]);
    __syncthreads();
    if (!dead) {
#pragma unroll
      for (int cc = 0; cc < 2; ++cc) {
        const bf16x8 v = *(const bf16x8*)&ld[col * 72 + (quad * 2 + cc) * 8];
        *(bf16x8*)(OUT + (size_t)(n0 + col) * 64 + (quad * 2 + cc) * 8) = v;
      }
    }
  }
}

// ======================= message MLP (MFMA) — used once for pass 0 ===========
__global__ void __launch_bounds__(256) msg_mfma_k(
    const unsigned short* __restrict__ Xb, const unsigned short* __restrict__ Wp,
    const float* __restrict__ B1, const float* __restrict__ B2,
    unsigned short* __restrict__ MSGb, int N) {
  __shared__ unsigned short lds[4][16 * 72];
  const int wave = threadIdx.x >> 6, l = threadIdx.x & 63;
  const int col = l & 15, quad = l >> 4;
  const int n0_raw = blockIdx.x * 64 + wave * 16;
  const bool dead = n0_raw >= N;
  const int n0 = dead ? 0 : n0_raw;

  const unsigned short* xrow = Xb + (size_t)(n0 + col) * 64 + quad * 8;
  const bf16x8 a0 = *(const bf16x8*)xrow;
  const bf16x8 a1 = *(const bf16x8*)(xrow + 32);
  const bf16x8* W1p = (const bf16x8*)Wp;
  const bf16x8* W2p = (const bf16x8*)(Wp + 4096);

  f32x4 acc[4];
#pragma unroll
  for (int t = 0; t < 4; ++t) {
    const float b = B1[col + 16 * t];
    acc[t] = f32x4{b, b, b, b};
  }
#pragma unroll
  for (int t = 0; t < 4; ++t) {
    acc[t] = __builtin_amdgcn_mfma_f32_16x16x32_bf16(a0, W1p[t * 64 + l], acc[t], 0, 0, 0);
    acc[t] = __builtin_amdgcn_mfma_f32_16x16x32_bf16(a1, W1p[(4 + t) * 64 + l], acc[t], 0, 0, 0);
  }
  unsigned short* ld = lds[wave];
#pragma unroll
  for (int t = 0; t < 4; ++t)
#pragma unroll
    for (int r = 0; r < 4; ++r)
      ld[(quad * 4 + r) * 72 + col + 16 * t] = f2bf(fmaxf(acc[t][r], 0.0f));
  __syncthreads();
  const bf16x8 h0 = *(const bf16x8*)&ld[col * 72 + quad * 8];
  const bf16x8 h1 = *(const bf16x8*)&ld[col * 72 + 32 + quad * 8];
  f32x4 o[4];
#pragma unroll
  for (int t = 0; t < 4; ++t) {
    const float b = B2[col + 16 * t];
    o[t] = f32x4{b, b, b, b};
  }
#pragma unroll
  for (int t = 0; t < 4; ++t) {
    o[t] = __builtin_amdgcn_mfma_f32_16x16x32_bf16(h0, W2p[t * 64 + l], o[t], 0, 0, 0);
    o[t] = __builtin_amdgcn_mfma_f32_16x16x32_bf16(h1, W2p[(4 + t) * 64 + l], o[t], 0, 0, 0);
  }
  __syncthreads();
#pragma unroll
  for (int t = 0; t < 4; ++t)
#pragma unroll
    for (int r = 0; r < 4; ++r)
      ld[(quad * 4 + r) * 72 + col + 16 * t] = f2bf(o[t][r]);
  __syncthreads();
  if (!dead) {
#pragma unroll
    for (int cc = 0; cc < 2; ++cc) {
      const bf16x8 v = *(const bf16x8*)&ld[col * 72 + (quad * 2 + cc) * 8];
      *(bf16x8*)(MSGb + (size_t)(n0 + col) * 64 + (quad * 2 + cc) * 8) = v;
    }
  }
}

// ==== fully-fused pass: CSR-aggregate + gate/upd/mix/LN + next-layer msg =====
// Rows are processed in DEGREE-SORTED order via perm (group-local node ids):
// a wave's 16 rows have near-equal degree, removing the max-of-16 straggler
// cost in the aggregate loop (degrees ~Poisson: max/mean ~ 1.45-1.6x).
// All row-indexed accesses go through perm; feature-indexed math unchanged.
template <int WITH_MSG>
__global__ void __launch_bounds__(256) pass_mfma_k(
    const int* __restrict__ row_ptr, const unsigned* __restrict__ adj,
    const float* __restrict__ degi, const unsigned short* __restrict__ MSGsrc,
    const unsigned short* __restrict__ NODEb, const int* __restrict__ perm,
    const unsigned short* __restrict__ gWp, const unsigned short* __restrict__ uW1p,
    const unsigned short* __restrict__ uW2p, const float* __restrict__ gB,
    const float* __restrict__ uB1, const float* __restrict__ uB2,
    const float* __restrict__ LNG, const float* __restrict__ LNB,
    const unsigned short* __restrict__ mWp,  // next layer msg W1|W2 (packed)
    const float* __restrict__ mB1, const float* __restrict__ mB2,
    float* __restrict__ OUTf, unsigned short* __restrict__ OUTb,
    unsigned short* __restrict__ MSGdst, int base, int N) {
  __shared__ unsigned short lds[4][16 * 72];
  const int wave = threadIdx.x >> 6, l = threadIdx.x & 63;
  const int col = l & 15, quad = l >> 4;
  const int n0_raw = blockIdx.x * 64 + wave * 16;
  const bool dead = n0_raw >= N;
  const int n0 = dead ? 0 : n0_raw;

  // ---- degree-sorted row indirection (group-local node ids) ----
  const int lcol = perm[base + n0 + col];  // node for this lane's A-frag row
  int pr[4];                               // nodes for this lane's C rows
#pragma unroll
  for (int j = 0; j < 4; ++j) pr[j] = perm[base + n0 + quad * 4 + j];

  // ---- phase 1: aggregate (in-register A-frag build) ----
  const int r = base + lcol;
  const int ps = row_ptr[r], pe = row_ptr[r + 1];
  float acc0[8], acc1[8];
#pragma unroll
  for (int j = 0; j < 8; ++j) { acc0[j] = 0.0f; acc1[j] = 0.0f; }
  int p = ps;
  for (; p + 4 <= pe; p += 4) {  // x4 unroll: 8 gathers in flight per lane
    unsigned av[4];
#pragma unroll
    for (int j = 0; j < 4; ++j) av[j] = adj[p + j];
    bf16x8 m0[4], m1[4];
#pragma unroll
    for (int j = 0; j < 4; ++j) {
      const unsigned short* m = MSGsrc + (size_t)(av[j] >> 14) * 64 + quad * 8;
      m0[j] = *(const bf16x8*)m;
      m1[j] = *(const bf16x8*)(m + 32);
    }
#pragma unroll
    for (int j = 0; j < 4; ++j) {
      const float w = (float)(av[j] & 16383u) * WQ_INV;
      const unsigned* u0 = (const unsigned*)&m0[j];
      const unsigned* u1 = (const unsigned*)&m1[j];
#pragma unroll
      for (int q = 0; q < 4; ++q) {
        acc0[2 * q] = fmaf(__uint_as_float(u0[q] << 16), w, acc0[2 * q]);
        acc0[2 * q + 1] = fmaf(__uint_as_float(u0[q] & 0xffff0000u), w, acc0[2 * q + 1]);
        acc1[2 * q] = fmaf(__uint_as_float(u1[q] << 16), w, acc1[2 * q]);
        acc1[2 * q + 1] = fmaf(__uint_as_float(u1[q] & 0xffff0000u), w, acc1[2 * q + 1]);
      }
    }
  }
  for (; p + 2 <= pe; p += 2) {  // x2 tail
    const unsigned avA = adj[p], avB = adj[p + 1];
    const unsigned short* mA = MSGsrc + (size_t)(avA >> 14) * 64 + quad * 8;
    const unsigned short* mB = MSGsrc + (size_t)(avB >> 14) * 64 + quad * 8;
    const bf16x8 mA0 = *(const bf16x8*)mA;
    const bf16x8 mA1 = *(const bf16x8*)(mA + 32);
    const bf16x8 mB0 = *(const bf16x8*)mB;
    const bf16x8 mB1v = *(const bf16x8*)(mB + 32);
    const float wA = (float)(avA & 16383u) * WQ_INV;
    const float wB = (float)(avB & 16383u) * WQ_INV;
    const unsigned* uA0 = (const unsigned*)&mA0;
    const unsigned* uA1 = (const unsigned*)&mA1;
    const unsigned* uB0 = (const unsigned*)&mB0;
    const unsigned* uB1v = (const unsigned*)&mB1v;
#pragma unroll
    for (int q = 0; q < 4; ++q) {
      acc0[2 * q] = fmaf(__uint_as_float(uA0[q] << 16), wA, acc0[2 * q]);
      acc0[2 * q + 1] = fmaf(__uint_as_float(uA0[q] & 0xffff0000u), wA, acc0[2 * q + 1]);
      acc1[2 * q] = fmaf(__uint_as_float(uA1[q] << 16), wA, acc1[2 * q]);
      acc1[2 * q + 1] = fmaf(__uint_as_float(uA1[q] & 0xffff0000u), wA, acc1[2 * q + 1]);
      acc0[2 * q] = fmaf(__uint_as_float(uB0[q] << 16), wB, acc0[2 * q]);
      acc0[2 * q + 1] = fmaf(__uint_as_float(uB0[q] & 0xffff0000u), wB, acc0[2 * q + 1]);
      acc1[2 * q] = fmaf(__uint_as_float(uB1v[q] << 16), wB, acc1[2 * q]);
      acc1[2 * q + 1] = fmaf(__uint_as_float(uB1v[q] & 0xffff0000u), wB, acc1[2 * q + 1]);
    }
  }
  if (p < pe) {
    const unsigned av = adj[p];
    const unsigned short* m = MSGsrc + (size_t)(av >> 14) * 64 + quad * 8;
    const bf16x8 m0 = *(const bf16x8*)m;
    const bf16x8 m1 = *(const bf16x8*)(m + 32);
    const float w = (float)(av & 16383u) * WQ_INV;
    const unsigned* u0 = (const unsigned*)&m0;
    const unsigned* u1 = (const unsigned*)&m1;
#pragma unroll
    for (int q = 0; q < 4; ++q) {
      acc0[2 * q] = fmaf(__uint_as_float(u0[q] << 16), w, acc0[2 * q]);
      acc0[2 * q + 1] = fmaf(__uint_as_float(u0[q] & 0xffff0000u), w, acc0[2 * q + 1]);
      acc1[2 * q] = fmaf(__uint_as_float(u1[q] << 16), w, acc1[2 * q]);
      acc1[2 * q + 1] = fmaf(__uint_as_float(u1[q] & 0xffff0000u), w, acc1[2 * q + 1]);
    }
  }
  const float di = degi[r];
  bf16x8 aA0, aA1;
#pragma unroll
  for (int j = 0; j < 8; ++j) {
    aA0[j] = (short)f2bf(acc0[j] * di);
    aA1[j] = (short)f2bf(acc1[j] * di);
  }

  // ---- phase 2: gate + upd1 (MFMA) ----
  const unsigned short* nrow = NODEb + (size_t)lcol * 64 + quad * 8;
  const bf16x8 aN0 = *(const bf16x8*)nrow;
  const bf16x8 aN1 = *(const bf16x8*)(nrow + 32);
  const bf16x8* gW = (const bf16x8*)gWp;
  const bf16x8* uW1 = (const bf16x8*)uW1p;
  const bf16x8* uW2 = (const bf16x8*)uW2p;

  f32x4 g[4], u[4];
#pragma unroll
  for (int t = 0; t < 4; ++t) {
    const float bg = gB[col + 16 * t], bu = uB1[col + 16 * t];
    g[t] = f32x4{bg, bg, bg, bg};
    u[t] = f32x4{bu, bu, bu, bu};
  }
#pragma unroll
  for (int t = 0; t < 4; ++t) {
    g[t] = __builtin_amdgcn_mfma_f32_16x16x32_bf16(aA0, gW[t * 64 + l], g[t], 0, 0, 0);
    g[t] = __builtin_amdgcn_mfma_f32_16x16x32_bf16(aA1, gW[(4 + t) * 64 + l], g[t], 0, 0, 0);
    g[t] = __builtin_amdgcn_mfma_f32_16x16x32_bf16(aN0, gW[(8 + t) * 64 + l], g[t], 0, 0, 0);
    g[t] = __builtin_amdgcn_mfma_f32_16x16x32_bf16(aN1, gW[(12 + t) * 64 + l], g[t], 0, 0, 0);
    u[t] = __builtin_amdgcn_mfma_f32_16x16x32_bf16(aA0, uW1[t * 64 + l], u[t], 0, 0, 0);
    u[t] = __builtin_amdgcn_mfma_f32_16x16x32_bf16(aA1, uW1[(4 + t) * 64 + l], u[t], 0, 0, 0);
    u[t] = __builtin_amdgcn_mfma_f32_16x16x32_bf16(aN0, uW1[(8 + t) * 64 + l], u[t], 0, 0, 0);
    u[t] = __builtin_amdgcn_mfma_f32_16x16x32_bf16(aN1, uW1[(12 + t) * 64 + l], u[t], 0, 0, 0);
  }
#pragma unroll
  for (int t = 0; t < 4; ++t)
#pragma unroll
    for (int r2 = 0; r2 < 4; ++r2) g[t][r2] = sigmoid_f(g[t][r2]);

  unsigned short* ld = lds[wave];
#pragma unroll
  for (int t = 0; t < 4; ++t)
#pragma unroll
    for (int r2 = 0; r2 < 4; ++r2)
      ld[(quad * 4 + r2) * 72 + col + 16 * t] = f2bf(fmaxf(u[t][r2], 0.0f));
  __syncthreads();
  const bf16x8 h0 = *(const bf16x8*)&ld[col * 72 + quad * 8];
  const bf16x8 h1 = *(const bf16x8*)&ld[col * 72 + 32 + quad * 8];
  f32x4 o[4];
#pragma unroll
  for (int t = 0; t < 4; ++t) {
    const float b = uB2[col + 16 * t];
    o[t] = f32x4{b, b, b, b};
  }
#pragma unroll
  for (int t = 0; t < 4; ++t) {
    o[t] = __builtin_amdgcn_mfma_f32_16x16x32_bf16(h0, uW2[t * 64 + l], o[t], 0, 0, 0);
    o[t] = __builtin_amdgcn_mfma_f32_16x16x32_bf16(h1, uW2[(4 + t) * 64 + l], o[t], 0, 0, 0);
  }
  // gate mix (bf16 node carry, C-layout gather through perm) + LayerNorm
  float om[4][4];
#pragma unroll
  for (int t = 0; t < 4; ++t)
#pragma unroll
    for (int r2 = 0; r2 < 4; ++r2) {
      const float nd = bf2f(NODEb[(size_t)pr[r2] * 64 + col + 16 * t]);
      om[t][r2] = fmaf(g[t][r2], o[t][r2] - nd, nd);
    }
  float outv[4][4];
#pragma unroll
  for (int r2 = 0; r2 < 4; ++r2) {
    float s1 = (om[0][r2] + om[1][r2]) + (om[2][r2] + om[3][r2]);
    float s2 = fmaf(om[0][r2], om[0][r2], fmaf(om[1][r2], om[1][r2],
                fmaf(om[2][r2], om[2][r2], om[3][r2] * om[3][r2])));
#pragma unroll
    for (int off = 1; off < 16; off <<= 1) {
      s1 += __shfl_xor(s1, off, 64);
      s2 += __shfl_xor(s2, off, 64);
    }
    const float m = s1 * (1.0f / 64.0f);
    const float var = s2 * (1.0f / 64.0f) - m * m;
    const float rr = rsqrtf(var + 1e-3f);
#pragma unroll
    for (int t = 0; t < 4; ++t)
      outv[t][r2] = fmaf((om[t][r2] - m) * rr, LNG[col + 16 * t], LNB[col + 16 * t]);
  }
  if (OUTf != nullptr && !dead) {
#pragma unroll
    for (int t = 0; t < 4; ++t)
#pragma unroll
      for (int r2 = 0; r2 < 4; ++r2)
        OUTf[(size_t)pr[r2] * 64 + col + 16 * t] = outv[t][r2];
  }
  __syncthreads();
#pragma unroll
  for (int t = 0; t < 4; ++t)
#pragma unroll
    for (int r2 = 0; r2 < 4; ++r2)
      ld[(quad * 4 + r2) * 72 + col + 16 * t] = f2bf(outv[t][r2]);
  __syncthreads();
  if (OUTb != nullptr && !dead) {
#pragma unroll
    for (int cc = 0; cc < 2; ++cc) {
      const bf16x8 v = *(const bf16x8*)&ld[col * 72 + (quad * 2 + cc) * 8];
      *(bf16x8*)(OUTb + (size_t)lcol * 64 + (quad * 2 + cc) * 8) = v;
    }
  }

  if constexpr (WITH_MSG) {
    // ---- phase 3: next layer's message MLP on the just-updated rows ----
    const bf16x8 x0 = *(const bf16x8*)&ld[col * 72 + quad * 8];
    const bf16x8 x1 = *(const bf16x8*)&ld[col * 72 + 32 + quad * 8];
    const bf16x8* W1p = (const bf16x8*)mWp;
    const bf16x8* W2p = (const bf16x8*)(mWp + 4096);
    f32x4 macc[4];
#pragma unroll
    for (int t = 0; t < 4; ++t) {
      const float b = mB1[col + 16 * t];
      macc[t] = f32x4{b, b, b, b};
    }
#pragma unroll
    for (int t = 0; t < 4; ++t) {
      macc[t] = __builtin_amdgcn_mfma_f32_16x16x32_bf16(x0, W1p[t * 64 + l], macc[t], 0, 0, 0);
      macc[t] = __builtin_amdgcn_mfma_f32_16x16x32_bf16(x1, W1p[(4 + t) * 64 + l], macc[t], 0, 0, 0);
    }
    __syncthreads();
#pragma unroll
    for (int t = 0; t < 4; ++t)
#pragma unroll
      for (int r2 = 0; r2 < 4; ++r2)
        ld[(quad * 4 + r2) * 72 + col + 16 * t] = f2bf(fmaxf(macc[t][r2], 0.0f));
    __syncthreads();
    const bf16x8 mh0 = *(const bf16x8*)&ld[col * 72 + quad * 8];
    const bf16x8 mh1 = *(const bf16x8*)&ld[col * 72 + 32 + quad * 8];
    f32x4 mo[4];
#pragma unroll
    for (int t = 0; t < 4; ++t) {
      const float b = mB2[col + 16 * t];
      mo[t] = f32x4{b, b, b, b};
    }
#pragma unroll
    for (int t = 0; t < 4; ++t) {
      mo[t] = __builtin_amdgcn_mfma_f32_16x16x32_bf16(mh0, W2p[t * 64 + l], mo[t], 0, 0, 0);
      mo[t] = __builtin_amdgcn_mfma_f32_16x16x32_bf16(mh1, W2p[(4 + t) * 64 + l], mo[t], 0, 0, 0);
    }
    __syncthreads();
#pragma unroll
    for (int t = 0; t < 4; ++t)
#pragma unroll
      for (int r2 = 0; r2 < 4; ++r2)
        ld[(quad * 4 + r2) * 72 + col + 16 * t] = f2bf(mo[t][r2]);
    __syncthreads();
    if (!dead) {
#pragma unroll
      for (int cc = 0; cc < 2; ++cc) {
        const bf16x8 v = *(const bf16x8*)&ld[col * 72 + (quad * 2 + cc) * 8];
        *(bf16x8*)(MSGdst + (size_t)lcol * 64 + (quad * 2 + cc) * 8) = v;
      }
    }
  }
}

// ===== edge weight + degree count w/ captured slot index (atomic return) =====
__global__ void __launch_bounds__(256) edgew_k(
    const int* __restrict__ S, const int* __restrict__ D,
    const float* __restrict__ EFX, const unsigned short* __restrict__ PA,
    const unsigned short* __restrict__ PB, const float* __restrict__ W1C,
    const float* __restrict__ W2, const float* __restrict__ B2,
    unsigned long long* __restrict__ stagedD,
    unsigned long long* __restrict__ stagedS,
    int* __restrict__ counts, int baseD, int baseS, int E) {
  const int l = threadIdx.x & 63;
  const int g = l >> 3, c = l & 7;
  float wc[8][8];
#pragma unroll
  for (int i = 0; i < 8; ++i) {
    const float4 v0 = *(const float4*)(W1C + i * 64 + c * 8);
    const float4 v1 = *(const float4*)(W1C + i * 64 + c * 8 + 4);
    wc[i][0] = v0.x; wc[i][1] = v0.y; wc[i][2] = v0.z; wc[i][3] = v0.w;
    wc[i][4] = v1.x; wc[i][5] = v1.y; wc[i][6] = v1.z; wc[i][7] = v1.w;
  }
  float w2c[8];
  {
    const float4 a0 = *(const float4*)(W2 + c * 8);
    const float4 a1 = *(const float4*)(W2 + c * 8 + 4);
    w2c[0] = a0.x; w2c[1] = a0.y; w2c[2] = a0.z; w2c[3] = a0.w;
    w2c[4] = a1.x; w2c[5] = a1.y; w2c[6] = a1.z; w2c[7] = a1.w;
  }
  const float b2 = B2[0];
  const int wave_id = blockIdx.x * 4 + (threadIdx.x >> 6);
  const int nwaves = gridDim.x * 4;
  for (int t0 = wave_id * 8; t0 < E; t0 += nwaves * 8) {
    const int e = t0 + g;
    const bool ok = e < E;
    const int ee = ok ? e : E - 1;
    const int s = __builtin_nontemporal_load(S + ee);
    const int d = __builtin_nontemporal_load(D + ee);
    // issue slot-index atomics EARLY; latency hides under the MLP below
    int kd = 0, ks = 0;
    const int rd = baseD + d, rs = baseS + s;
    if (ok && c == 0) {
      kd = atomicAdd(&counts[rd], 1);
      ks = atomicAdd(&counts[rs], 1);
    }
    const bf16x8 pa = *(const bf16x8*)(PA + (size_t)s * 64 + c * 8);
    const bf16x8 pb = *(const bf16x8*)(PB + (size_t)d * 64 + c * 8);
    const f32x4 ef0 =
        __builtin_nontemporal_load((const f32x4*)(EFX + (size_t)ee * 8));
    const f32x4 ef1 =
        __builtin_nontemporal_load((const f32x4*)(EFX + (size_t)ee * 8 + 4));
    const unsigned* pau = (const unsigned*)&pa;
    const unsigned* pbu = (const unsigned*)&pb;
    float h[8];
#pragma unroll
    for (int q = 0; q < 4; ++q) {
      h[2 * q] = __uint_as_float(pau[q] << 16) + __uint_as_float(pbu[q] << 16);
      h[2 * q + 1] = __uint_as_float(pau[q] & 0xffff0000u) +
                     __uint_as_float(pbu[q] & 0xffff0000u);
    }
    const float ef[8] = {ef0[0], ef0[1], ef0[2], ef0[3],
                         ef1[0], ef1[1], ef1[2], ef1[3]};
#pragma unroll
    for (int i = 0; i < 8; ++i)
#pragma unroll
      for (int j = 0; j < 8; ++j) h[j] = fmaf(ef[i], wc[i][j], h[j]);
    float t = 0.0f;
#pragma unroll
    for (int j = 0; j < 8; ++j) t = fmaf(fmaxf(h[j], 0.0f), w2c[j], t);
#pragma unroll
    for (int off = 1; off < 8; off <<= 1) t += __shfl_xor(t, off, 64);
    if (ok && c == 0) {
      const float w = sigmoid_f(t + b2);
      const unsigned w14 = (unsigned)(w * WQ_SCALE + 0.5f);
      stagedD[e] =
          (unsigned long long)((unsigned)rd | ((unsigned)kd << 19)) |
          ((unsigned long long)(((unsigned)s << 14) | w14) << 32);
      stagedS[e] =
          (unsigned long long)((unsigned)rs | ((unsigned)ks << 19)) |
          ((unsigned long long)(((unsigned)d << 14) | w14) << 32);
    }
  }
}

// ==== atomic-free CSR fill: bin=blockIdx&7 pins a row range to one XCD =====
__global__ void __launch_bounds__(256) fill_staged_k(
    const unsigned long long* __restrict__ staged,
    const int* __restrict__ row_ptr, unsigned* __restrict__ adj) {
  const int bin = blockIdx.x & 7;
  const int blk = blockIdx.x >> 3;
  const int nblk = gridDim.x >> 3;
  const int lo = (bin == 0) ? 0 : c_bin_hi[bin - 1];
  const int hi = c_bin_hi[bin];
  const int slo = c_seg_lo[bin], shi = c_seg_hi[bin];
  for (int i = slo + blk * 256 + threadIdx.x; i < shi; i += nblk * 256) {
    const unsigned long long v = __builtin_nontemporal_load(staged + i);
    const int row = (int)(v & 0x7ffffull);
    if (row >= lo && row < hi) {
      const int k = (int)((v >> 19) & 0x1fffull);
      adj[row_ptr[row] + k] = (unsigned)(v >> 32);
    }
  }
}

__global__ void __launch_bounds__(256) degi_k(const int* __restrict__ row_ptr,
                                             const unsigned* __restrict__ adj,
                                             float* __restrict__ degi) {
  const int r = blockIdx.x * 256 + threadIdx.x;
  if (r >= R_TOT) return;
  const int s = row_ptr[r], e = row_ptr[r + 1];
  float d = 0.0f;
  for (int p = s; p < e; ++p) d += (float)(adj[p] & 16383u) * WQ_INV;
  degi[r] = 1.0f / fmaxf(d, 1.0f);
}

// ==== degree-sorted permutation build (counting sort per row-group) =========
// 1) histogram degrees (capture within-bin position via atomic return)
__global__ void __launch_bounds__(256) dsort1_k(const int* __restrict__ counts,
                                                int* __restrict__ hist,
                                                int* __restrict__ kk) {
  const int r = blockIdx.x * 256 + threadIdx.x;
  if (r >= R_TOT) return;
  const int grp = row_group(r);
  const int bin = min(counts[r], 255);
  kk[r] = atomicAdd(&hist[grp * 256 + bin], 1);
}
// 2) exclusive scan of each group's 256 bins (1 block)
__global__ void __launch_bounds__(256) dsort2_k(int* __restrict__ hist) {
  __shared__ int sd[256];
  const int t = threadIdx.x;
  for (int g = 0; g < 4; ++g) {
    const int v = hist[g * 256 + t];
    sd[t] = v;
    __syncthreads();
    for (int off = 1; off < 256; off <<= 1) {
      const int add = (t >= off) ? sd[t - off] : 0;
      __syncthreads();
      sd[t] += add;
      __syncthreads();
    }
    hist[g * 256 + t] = sd[t] - v;  // exclusive
    __syncthreads();
  }
}
// 3) scatter: perm[grp_base + binbase + k] = group-local node id
__global__ void __launch_bounds__(256) dsort3_k(const int* __restrict__ counts,
                                                const int* __restrict__ hist,
                                                const int* __restrict__ kk,
                                                int* __restrict__ perm) {
  const int r = blockIdx.x * 256 + threadIdx.x;
  if (r >= R_TOT) return;
  const int grp = row_group(r);
  const int bin = min(counts[r], 255);
  const int gb = c_grp_base[grp];
  perm[gb + hist[grp * 256 + bin] + kk[r]] = r - gb;
}

__global__ void __launch_bounds__(256) scan1_k(const int* __restrict__ in,
                                               int* __restrict__ bsum) {
  __shared__ int sd[256];
  const int t = threadIdx.x;
  const int base = blockIdx.x * SCAN_CHUNK + t * 8;
  int s = 0;
#pragma unroll
  for (int i = 0; i < 8; ++i) {
    const int idx = base + i;
    s += (idx < R_TOT) ? in[idx] : 0;
  }
  sd[t] = s;
  __syncthreads();
  for (int off = 128; off > 0; off >>= 1) {
    if (t < off) sd[t] += sd[t + off];
    __syncthreads();
  }
  if (t == 0) bsum[blockIdx.x] = sd[0];
}

__global__ void __launch_bounds__(256) scan2_k(int* __restrict__ bsum,
                                               int* __restrict__ row_ptr) {
  __shared__ int sd[256];
  const int t = threadIdx.x;
  const int v = (t < SCAN_NB) ? bsum[t] : 0;
  sd[t] = v;
  __syncthreads();
  for (int off = 1; off < 256; off <<= 1) {
    const int add = (t >= off) ? sd[t - off] : 0;
    __syncthreads();
    sd[t] += add;
    __syncthreads();
  }
  if (t < SCAN_NB) bsum[t] = sd[t] - v;
  if (t == 255) row_ptr[R_TOT] = sd[255];
}

__global__ void __launch_bounds__(256) scan3_k(const int* __restrict__ in,
                                               const int* __restrict__ bsum,
                                               int* __restrict__ out) {
  __shared__ int sd[256];
  const int t = threadIdx.x;
  const int base = blockIdx.x * SCAN_CHUNK + t * 8;
  int loc[8];
  int s = 0;
#pragma unroll
  for (int i = 0; i < 8; ++i) {
    loc[i] = s;
    const int idx = base + i;
    s += (idx < R_TOT) ? in[idx] : 0;
  }
  sd[t] = s;
  __syncthreads();
  const int v = s;
  for (int off = 1; off < 256; off <<= 1) {
    const int add = (t >= off) ? sd[t - off] : 0;
    __syncthreads();
    sd[t] += add;
    __syncthreads();
  }
  const int off0 = bsum[blockIdx.x] + (sd[t] - v);
#pragma unroll
  for (int i = 0; i < 8; ++i) {
    const int idx = base + i;
    if (idx < R_TOT) out[idx] = off0 + loc[i];
  }
}

}  // namespace

extern "C" void kernel_launch(void* const* d_in, const int* in_sizes, int n_in,
                              void* d_out, int out_size, void* d_ws, size_t ws_size,
                              hipStream_t stream) {
  (void)in_sizes; (void)n_in; (void)out_size; (void)ws_size;

  const float* variable_features   = (const float*)d_in[0];
  const float* constraint_features = (const float*)d_in[1];
  const float* cut_features        = (const float*)d_in[2];
  const float* vc_ef = (const float*)d_in[3];
  const float* vk_ef = (const float*)d_in[4];
  const int* vc_edges = (const int*)d_in[5];
  const int* vk_edges = (const int*)d_in[6];
  const int *vc_s = vc_edges, *vc_d = vc_edges + EVC;
  const int *vk_s = vk_edges, *vk_d = vk_edges + EVK;
  const float* var_w1  = (const float*)d_in[7];
  const float* var_b1  = (const float*)d_in[8];
  const float* var_w2  = (const float*)d_in[9];
  const float* var_b2  = (const float*)d_in[10];
  const float* cons_w1 = (const float*)d_in[11];
  const float* cons_b1 = (const float*)d_in[12];
  const float* cons_w2 = (const float*)d_in[13];
  const float* cons_b2 = (const float*)d_in[14];
  const float* cut_w1  = (const float*)d_in[15];
  const float* cut_b1  = (const float*)d_in[16];
  const float* cut_w2  = (const float*)d_in[17];
  const float* cut_b2  = (const float*)d_in[18];
  const float* ewvc_w1 = (const float*)d_in[19];
  const float* ewvc_b1 = (const float*)d_in[20];
  const float* ewvc_w2 = (const float*)d_in[21];
  const float* ewvc_b2 = (const float*)d_in[22];
  const float* ewvk_w1 = (const float*)d_in[23];
  const float* ewvk_b1 = (const float*)d_in[24];
  const float* ewvk_w2 = (const float*)d_in[25];
  const float* ewvk_b2 = (const float*)d_in[26];
  const float* mp_msg_w1 = (const float*)d_in[27];
  const float* mp_msg_b1 = (const float*)d_in[28];
  const float* mp_msg_w2 = (const float*)d_in[29];
  const float* mp_msg_b2 = (const float*)d_in[30];
  const float* mp_gate_w = (const float*)d_in[31];
  const float* mp_gate_b = (const float*)d_in[32];
  const float* mp_upd_w1 = (const float*)d_in[33];
  const float* mp_upd_b1 = (const float*)d_in[34];
  const float* mp_upd_w2 = (const float*)d_in[35];
  const float* mp_upd_b2 = (const float*)d_in[36];
  const float* mp_ln_g   = (const float*)d_in[37];
  const float* mp_ln_b   = (const float*)d_in[38];

  // ---- workspace carve ----
  char* wp = (char*)d_ws;
  auto take = [&](size_t nbytes) {
    char* p = wp;
    wp += (nbytes + 255) & ~(size_t)255;
    return p;
  };
  unsigned short* h_var_b  = (unsigned short*)take((size_t)NV * 64 * 2);
  unsigned short* h_cons_b = (unsigned short*)take((size_t)NC * 64 * 2);
  unsigned short* h_cut_b  = (unsigned short*)take((size_t)NK * 64 * 2);
  unsigned short* msg_ping = (unsigned short*)take((size_t)NV * 64 * 2);
  unsigned short* msg_pong = (unsigned short*)take((size_t)NV * 64 * 2);
  unsigned short* pa = (unsigned short*)take((size_t)NV * 64 * 2);
  unsigned short* pb = (unsigned short*)take((size_t)NC * 64 * 2);
  unsigned short* qa = (unsigned short*)take((size_t)NV * 64 * 2);
  unsigned short* qb = (unsigned short*)take((size_t)NK * 64 * 2);
  unsigned short* packW = (unsigned short*)take((size_t)15 * PACK_PER_LAYER * 2);
  unsigned short* packE = (unsigned short*)take((size_t)PE_TOTAL * 2);
  int* row_ptr = (int*)take((size_t)(R_TOT + 1) * 4);
  int* counts  = (int*)take((size_t)R_TOT * 4);
  int* bsum    = (int*)take(256 * 4);
  int* hist    = (int*)take(1024 * 4);
  int* kk      = (int*)take((size_t)R_TOT * 4);
  int* perm    = (int*)take((size_t)R_TOT * 4);
  float* degi  = (float*)take((size_t)R_TOT * 4);
  unsigned* adj = (unsigned*)take((size_t)(2 * EVC + 2 * EVK) * 4);

  // ---- time-sliced alias (no extra workspace) ----
  unsigned long long* staged = (unsigned long long*)msg_ping;

  // ---- init counts + hist (filled during edgew / dsort) ----
  hipMemsetAsync(counts, 0, (size_t)R_TOT * 4, stream);
  hipMemsetAsync(hist, 0, 1024 * 4, stream);

  // ---- pack weights (MP layers + embeddings/edge-weight mats) ----
  pack_k<<<15, 256, 0, stream>>>(mp_msg_w1, mp_msg_w2, mp_gate_w, mp_upd_w1,
                                 mp_upd_w2, packW);
  pack_emb_k<<<10, 256, 0, stream>>>(var_w1, var_w2, cons_w1, cons_w2, cut_w1,
                                     cut_w2, ewvc_w1, ewvk_w1, packE);

  // ---- embeddings (MFMA, bf16 out) ----
  emb_mfma_k<19><<<(NV + 63) / 64, 256, 0, stream>>>(
      variable_features, packE + PE_VAR_W1, packE + PE_VAR_W2, var_b1, var_b2,
      h_var_b, NV);
  emb_mfma_k<5><<<(NC + 63) / 64, 256, 0, stream>>>(
      constraint_features, packE + PE_CONS_W1, packE + PE_CONS_W2, cons_b1,
      cons_b2, h_cons_b, NC);
  emb_mfma_k<30><<<(NK + 63) / 64, 256, 0, stream>>>(
      cut_features, packE + PE_CUT_W1, packE + PE_CUT_W2, cut_b1, cut_b2,
      h_cut_b, NK);

  // ---- edge-weight per-node terms (MFMA; var does both projections) ----
  gemv_mfma_k<2><<<(NV + 63) / 64, 256, 0, stream>>>(
      h_var_b, packE + PE_EWVC_A, packE + PE_EWVK_A, nullptr, pa, qa, NV);
  gemv_mfma_k<1><<<(NC + 63) / 64, 256, 0, stream>>>(
      h_cons_b, packE + PE_EWVC_B, nullptr, ewvc_b1, pb, nullptr, NC);
  gemv_mfma_k<1><<<(NK + 63) / 64, 256, 0, stream>>>(
      h_cut_b, packE + PE_EWVK_B, nullptr, ewvk_b1, qb, nullptr, NK);

  // ---- edge weights + degree counts (atomic-return = CSR slot index) ----
  edgew_k<<<1024, 256, 0, stream>>>(vc_s, vc_d, vc_ef, pa, pb,
                                    ewvc_w1 + 128 * 64, ewvc_w2, ewvc_b2,
                                    staged, staged + EVC, counts, 0, NC, EVC);
  edgew_k<<<512, 256, 0, stream>>>(vk_s, vk_d, vk_ef, qa, qb,
                                   ewvk_w1 + 128 * 64, ewvk_w2, ewvk_b2,
                                   staged + 2 * EVC, staged + 2 * EVC + EVK,
                                   counts, NC + NV, NC + NV + NK, EVK);

  // ---- CSR scan + degree-sort perm + atomic-free XCD-local fill + 1/deg ----
  scan1_k<<<SCAN_NB, 256, 0, stream>>>(counts, bsum);
  scan2_k<<<1, 256, 0, stream>>>(bsum, row_ptr);
  scan3_k<<<SCAN_NB, 256, 0, stream>>>(counts, bsum, row_ptr);
  dsort1_k<<<(R_TOT + 255) / 256, 256, 0, stream>>>(counts, hist, kk);
  dsort2_k<<<1, 256, 0, stream>>>(hist);
  dsort3_k<<<(R_TOT + 255) / 256, 256, 0, stream>>>(counts, hist, kk, perm);
  fill_staged_k<<<8 * 192, 256, 0, stream>>>(staged, row_ptr, adj);
  degi_k<<<(R_TOT + 255) / 256, 256, 0, stream>>>(row_ptr, adj, degi);

  // ---- 15 fully-fused passes (agg + upd + next msg), msg ping-pong ----
  unsigned short* nodeb_t[4] = {h_cons_b, h_var_b, h_cut_b, h_var_b};
  const int Nd_t[4] = {NC, NV, NK, NV};
  const int base_t[4] = {0, NC, NC + NV, NC + NV + NK};

  // msg(0): over h_var with layer-0 msg weights -> ping
  msg_mfma_k<<<(NV + 63) / 64, 256, 0, stream>>>(
      h_var_b, packW, mp_msg_b1, mp_msg_b2, msg_ping, NV);

  for (int i = 0; i < 15; ++i) {
    const int d = i & 3;
    const int Nd = Nd_t[d], base = base_t[d];
    const unsigned short* Wl = packW + (size_t)i * PACK_PER_LAYER;
    const unsigned short* src = (i % 2 == 0) ? msg_ping : msg_pong;
    unsigned short* dst = (i % 2 == 0) ? msg_pong : msg_ping;

    if (i < 14) {
      const unsigned short* Wn = packW + (size_t)(i + 1) * PACK_PER_LAYER;
      pass_mfma_k<1><<<(Nd + 63) / 64, 256, 0, stream>>>(
          row_ptr, adj, degi, src, nodeb_t[d], perm, Wl + 8192, Wl + 16384,
          Wl + 24576, mp_gate_b + (size_t)i * 64, mp_upd_b1 + (size_t)i * 64,
          mp_upd_b2 + (size_t)i * 64, mp_ln_g + (size_t)i * 64,
          mp_ln_b + (size_t)i * 64, Wn, mp_msg_b1 + (size_t)(i + 1) * 64,
          mp_msg_b2 + (size_t)(i + 1) * 64, nullptr, nodeb_t[d], dst, base, Nd);
    } else {
      pass_mfma_k<0><<<(Nd + 63) / 64, 256, 0, stream>>>(
          row_ptr, adj, degi, src, nodeb_t[d], perm, Wl + 8192, Wl + 16384,
          Wl + 24576, mp_gate_b + (size_t)i * 64, mp_upd_b1 + (size_t)i * 64,
          mp_upd_b2 + (size_t)i * 64, mp_ln_g + (size_t)i * 64,
          mp_ln_b + (size_t)i * 64, nullptr, nullptr, nullptr,
          (float*)d_out, nullptr, nullptr, base, Nd);
    }
  }
}

// Round 9
// 800.343 us; speedup vs baseline: 1.7251x; 1.7251x over previous
//
#include <hip/hip_runtime.h>

#define DEVINL static __device__ __forceinline__

namespace {

typedef __attribute__((ext_vector_type(8))) short bf16x8;
typedef __attribute__((ext_vector_type(4))) float f32x4;

constexpr int NV = 100000;   // variables
constexpr int NC = 50000;    // constraints
constexpr int NK = 20000;    // cuts
constexpr int EVC = 800000;  // var-cons edges
constexpr int EVK = 200000;  // var-cut edges
constexpr int E_TOT2 = 2 * (EVC + EVK);  // 2M staged entries
constexpr int R_TOT = NC + NV + NK + NV;  // 270000 CSR rows
constexpr int SCAN_CHUNK = 2048;
constexpr int SCAN_NB = (R_TOT + SCAN_CHUNK - 1) / SCAN_CHUNK;  // 132
constexpr int PACK_PER_LAYER = 28672;  // ushort per layer of packed MP weights
constexpr float WQ_SCALE = 16383.0f;
constexpr float WQ_INV = 1.0f / 16383.0f;

// ---- atomic-free CSR fill: 8 row-range bins, XCD-pinned (blockIdx&7) ----
__constant__ int c_bin_hi[8] = {12500, 25000, 37500, 50000,
                                83334, 116667, 150000, 270000};
__constant__ int c_seg_lo[8] = {0, 0, 0, 0, EVC, EVC, EVC, 2 * EVC};
__constant__ int c_seg_hi[8] = {EVC, EVC, EVC, EVC,
                                2 * EVC, 2 * EVC, 2 * EVC, E_TOT2};

// packed embedding/edge-weight matrix offsets (ushort)
constexpr int PE_VAR_W1 = 0;      // Kpad=32 -> 2048
constexpr int PE_VAR_W2 = 2048;   // K=64   -> 4096
constexpr int PE_CONS_W1 = 6144;  // 2048
constexpr int PE_CONS_W2 = 8192;  // 4096
constexpr int PE_CUT_W1 = 12288;  // 2048
constexpr int PE_CUT_W2 = 14336;  // 4096
constexpr int PE_EWVC_A = 18432;  // 4096
constexpr int PE_EWVC_B = 22528;  // 4096
constexpr int PE_EWVK_A = 26624;  // 4096
constexpr int PE_EWVK_B = 30720;  // 4096
constexpr int PE_TOTAL = 34816;

DEVINL unsigned short f2bf(float f) {
  unsigned u = __float_as_uint(f);
  u = u + 0x7fffu + ((u >> 16) & 1u);  // RNE
  return (unsigned short)(u >> 16);
}
DEVINL float bf2f(unsigned short h) {
  return __uint_as_float((unsigned)h << 16);
}

DEVINL float sigmoid_f(float x) { return 1.0f / (1.0f + __expf(-x)); }

// ======================= weight packing (bf16 B-frag streams) ================
DEVINL void pack_mat(const float* __restrict__ src, int K, int Kpad,
                     unsigned short* __restrict__ dst, int tid) {
  const int ntup = (Kpad / 32) * 256;
  for (int tup = tid; tup < ntup; tup += 256) {
    const int lane = tup & 63;
    const int t = (tup >> 6) & 3;
    const int kb = tup >> 8;
    const int c = t * 16 + (lane & 15);
    const int k0 = kb * 32 + (lane >> 4) * 8;
#pragma unroll
    for (int jj = 0; jj < 8; ++jj)
      dst[tup * 8 + jj] =
          (k0 + jj < K) ? f2bf(src[(k0 + jj) * 64 + c]) : (unsigned short)0;
  }
}

__global__ void __launch_bounds__(256) pack_k(
    const float* __restrict__ mW1, const float* __restrict__ mW2,
    const float* __restrict__ gW, const float* __restrict__ uW1,
    const float* __restrict__ uW2, unsigned short* __restrict__ PW) {
  const int layer = blockIdx.x;  // 0..14
  unsigned short* out = PW + (size_t)layer * PACK_PER_LAYER;
  pack_mat(mW1 + (size_t)layer * 4096, 64, 64, out, threadIdx.x);
  pack_mat(mW2 + (size_t)layer * 4096, 64, 64, out + 4096, threadIdx.x);
  pack_mat(gW + (size_t)layer * 8192, 128, 128, out + 8192, threadIdx.x);
  pack_mat(uW1 + (size_t)layer * 8192, 128, 128, out + 16384, threadIdx.x);
  pack_mat(uW2 + (size_t)layer * 4096, 64, 64, out + 24576, threadIdx.x);
}

__global__ void __launch_bounds__(256) pack_emb_k(
    const float* __restrict__ var_w1, const float* __restrict__ var_w2,
    const float* __restrict__ cons_w1, const float* __restrict__ cons_w2,
    const float* __restrict__ cut_w1, const float* __restrict__ cut_w2,
    const float* __restrict__ ewvc_w1, const float* __restrict__ ewvk_w1,
    unsigned short* __restrict__ P) {
  switch (blockIdx.x) {
    case 0: pack_mat(var_w1, 19, 32, P + PE_VAR_W1, threadIdx.x); break;
    case 1: pack_mat(var_w2, 64, 64, P + PE_VAR_W2, threadIdx.x); break;
    case 2: pack_mat(cons_w1, 5, 32, P + PE_CONS_W1, threadIdx.x); break;
    case 3: pack_mat(cons_w2, 64, 64, P + PE_CONS_W2, threadIdx.x); break;
    case 4: pack_mat(cut_w1, 30, 32, P + PE_CUT_W1, threadIdx.x); break;
    case 5: pack_mat(cut_w2, 64, 64, P + PE_CUT_W2, threadIdx.x); break;
    case 6: pack_mat(ewvc_w1, 64, 64, P + PE_EWVC_A, threadIdx.x); break;
    case 7: pack_mat(ewvc_w1 + 64 * 64, 64, 64, P + PE_EWVC_B, threadIdx.x); break;
    case 8: pack_mat(ewvk_w1, 64, 64, P + PE_EWVK_A, threadIdx.x); break;
    case 9: pack_mat(ewvk_w1 + 64 * 64, 64, 64, P + PE_EWVK_B, threadIdx.x); break;
  }
}

// ======================= embedding MLP (MFMA, K1 padded to 32) ===============
template <int DIN>
__global__ void __launch_bounds__(256) emb_mfma_k(
    const float* __restrict__ X, const unsigned short* __restrict__ W1p_,
    const unsigned short* __restrict__ W2p_, const float* __restrict__ B1,
    const float* __restrict__ B2, unsigned short* __restrict__ OUTb, int N) {
  __shared__ unsigned short lds[4][16 * 72];
  const int wave = threadIdx.x >> 6, l = threadIdx.x & 63;
  const int col = l & 15, quad = l >> 4;
  const int n0_raw = blockIdx.x * 64 + wave * 16;
  const bool dead = n0_raw >= N;
  const int n0 = dead ? 0 : n0_raw;

  bf16x8 a0;
#pragma unroll
  for (int j = 0; j < 8; ++j) {
    const int k = quad * 8 + j;
    a0[j] = (k < DIN) ? (short)f2bf(X[(size_t)(n0 + col) * DIN + k]) : (short)0;
  }
  const bf16x8* W1p = (const bf16x8*)W1p_;
  const bf16x8* W2p = (const bf16x8*)W2p_;
  f32x4 acc[4];
#pragma unroll
  for (int t = 0; t < 4; ++t) {
    const float b = B1[col + 16 * t];
    acc[t] = f32x4{b, b, b, b};
  }
#pragma unroll
  for (int t = 0; t < 4; ++t)
    acc[t] = __builtin_amdgcn_mfma_f32_16x16x32_bf16(a0, W1p[t * 64 + l], acc[t], 0, 0, 0);
  unsigned short* ld = lds[wave];
#pragma unroll
  for (int t = 0; t < 4; ++t)
#pragma unroll
    for (int r = 0; r < 4; ++r)
      ld[(quad * 4 + r) * 72 + col + 16 * t] = f2bf(fmaxf(acc[t][r], 0.0f));
  __syncthreads();
  const bf16x8 h0 = *(const bf16x8*)&ld[col * 72 + quad * 8];
  const bf16x8 h1 = *(const bf16x8*)&ld[col * 72 + 32 + quad * 8];
  f32x4 o[4];
#pragma unroll
  for (int t = 0; t < 4; ++t) {
    const float b = B2[col + 16 * t];
    o[t] = f32x4{b, b, b, b};
  }
#pragma unroll
  for (int t = 0; t < 4; ++t) {
    o[t] = __builtin_amdgcn_mfma_f32_16x16x32_bf16(h0, W2p[t * 64 + l], o[t], 0, 0, 0);
    o[t] = __builtin_amdgcn_mfma_f32_16x16x32_bf16(h1, W2p[(4 + t) * 64 + l], o[t], 0, 0, 0);
  }
  __syncthreads();
#pragma unroll
  for (int t = 0; t < 4; ++t)
#pragma unroll
    for (int r = 0; r < 4; ++r)
      ld[(quad * 4 + r) * 72 + col + 16 * t] = f2bf(o[t][r]);
  __syncthreads();
  if (!dead) {
#pragma unroll
    for (int cc = 0; cc < 2; ++cc) {
      const bf16x8 v = *(const bf16x8*)&ld[col * 72 + (quad * 2 + cc) * 8];
      *(bf16x8*)(OUTb + (size_t)(n0 + col) * 64 + (quad * 2 + cc) * 8) = v;
    }
  }
}

// ======= edge-weight per-node GEMV (MFMA); NOUT=2 shares the A-frag =========
template <int NOUT>
__global__ void __launch_bounds__(256) gemv_mfma_k(
    const unsigned short* __restrict__ Xb, const unsigned short* __restrict__ WpA_,
    const unsigned short* __restrict__ WpB_, const float* __restrict__ Bias,
    unsigned short* __restrict__ OUT0, unsigned short* __restrict__ OUT1, int N) {
  __shared__ unsigned short lds[4][16 * 72];
  const int wave = threadIdx.x >> 6, l = threadIdx.x & 63;
  const int col = l & 15, quad = l >> 4;
  const int n0_raw = blockIdx.x * 64 + wave * 16;
  const bool dead = n0_raw >= N;
  const int n0 = dead ? 0 : n0_raw;
  const unsigned short* xrow = Xb + (size_t)(n0 + col) * 64 + quad * 8;
  const bf16x8 a0 = *(const bf16x8*)xrow;
  const bf16x8 a1 = *(const bf16x8*)(xrow + 32);
  unsigned short* ld = lds[wave];
#pragma unroll
  for (int m = 0; m < NOUT; ++m) {
    const bf16x8* Wp = (const bf16x8*)(m == 0 ? WpA_ : WpB_);
    unsigned short* OUT = (m == 0) ? OUT0 : OUT1;
    f32x4 acc[4];
#pragma unroll
    for (int t = 0; t < 4; ++t) {
      const float b = (Bias != nullptr) ? Bias[col + 16 * t] : 0.0f;
      acc[t] = f32x4{b, b, b, b};
    }
#pragma unroll
    for (int t = 0; t < 4; ++t) {
      acc[t] = __builtin_amdgcn_mfma_f32_16x16x32_bf16(a0, Wp[t * 64 + l], acc[t], 0, 0, 0);
      acc[t] = __builtin_amdgcn_mfma_f32_16x16x32_bf16(a1, Wp[(4 + t) * 64 + l], acc[t], 0, 0, 0);
    }
    if (m > 0) __syncthreads();
#pragma unroll
    for (int t = 0; t < 4; ++t)
#pragma unroll
      for (int r = 0; r < 4; ++r)
        ld[(quad * 4 + r) * 72 + col + 16 * t] = f2bf(acc[t][r]);
    __syncthreads();
    if (!dead) {
#pragma unroll
      for (int cc = 0; cc < 2; ++cc) {
        const bf16x8 v = *(const bf16x8*)&ld[col * 72 + (quad * 2 + cc) * 8];
        *(bf16x8*)(OUT + (size_t)(n0 + col) * 64 + (quad * 2 + cc) * 8) = v;
      }
    }
  }
}

// ======================= message MLP (MFMA) — used once for pass 0 ===========
__global__ void __launch_bounds__(256) msg_mfma_k(
    const unsigned short* __restrict__ Xb, const unsigned short* __restrict__ Wp,
    const float* __restrict__ B1, const float* __restrict__ B2,
    unsigned short* __restrict__ MSGb, int N) {
  __shared__ unsigned short lds[4][16 * 72];
  const int wave = threadIdx.x >> 6, l = threadIdx.x & 63;
  const int col = l & 15, quad = l >> 4;
  const int n0_raw = blockIdx.x * 64 + wave * 16;
  const bool dead = n0_raw >= N;
  const int n0 = dead ? 0 : n0_raw;

  const unsigned short* xrow = Xb + (size_t)(n0 + col) * 64 + quad * 8;
  const bf16x8 a0 = *(const bf16x8*)xrow;
  const bf16x8 a1 = *(const bf16x8*)(xrow + 32);
  const bf16x8* W1p = (const bf16x8*)Wp;
  const bf16x8* W2p = (const bf16x8*)(Wp + 4096);

  f32x4 acc[4];
#pragma unroll
  for (int t = 0; t < 4; ++t) {
    const float b = B1[col + 16 * t];
    acc[t] = f32x4{b, b, b, b};
  }
#pragma unroll
  for (int t = 0; t < 4; ++t) {
    acc[t] = __builtin_amdgcn_mfma_f32_16x16x32_bf16(a0, W1p[t * 64 + l], acc[t], 0, 0, 0);
    acc[t] = __builtin_amdgcn_mfma_f32_16x16x32_bf16(a1, W1p[(4 + t) * 64 + l], acc[t], 0, 0, 0);
  }
  unsigned short* ld = lds[wave];
#pragma unroll
  for (int t = 0; t < 4; ++t)
#pragma unroll
    for (int r = 0; r < 4; ++r)
      ld[(quad * 4 + r) * 72 + col + 16 * t] = f2bf(fmaxf(acc[t][r], 0.0f));
  __syncthreads();
  const bf16x8 h0 = *(const bf16x8*)&ld[col * 72 + quad * 8];
  const bf16x8 h1 = *(const bf16x8*)&ld[col * 72 + 32 + quad * 8];
  f32x4 o[4];
#pragma unroll
  for (int t = 0; t < 4; ++t) {
    const float b = B2[col + 16 * t];
    o[t] = f32x4{b, b, b, b};
  }
#pragma unroll
  for (int t = 0; t < 4; ++t) {
    o[t] = __builtin_amdgcn_mfma_f32_16x16x32_bf16(h0, W2p[t * 64 + l], o[t], 0, 0, 0);
    o[t] = __builtin_amdgcn_mfma_f32_16x16x32_bf16(h1, W2p[(4 + t) * 64 + l], o[t], 0, 0, 0);
  }
  __syncthreads();
#pragma unroll
  for (int t = 0; t < 4; ++t)
#pragma unroll
    for (int r = 0; r < 4; ++r)
      ld[(quad * 4 + r) * 72 + col + 16 * t] = f2bf(o[t][r]);
  __syncthreads();
  if (!dead) {
#pragma unroll
    for (int cc = 0; cc < 2; ++cc) {
      const bf16x8 v = *(const bf16x8*)&ld[col * 72 + (quad * 2 + cc) * 8];
      *(bf16x8*)(MSGb + (size_t)(n0 + col) * 64 + (quad * 2 + cc) * 8) = v;
    }
  }
}

// ==== fully-fused pass: CSR-aggregate + gate/upd/mix/LN + next-layer msg =====
// BARRIER-FREE: each wave uses only its own lds[wave] slice and all cross-lane
// exchange is within one 64-lane wave (LDS ops execute in program order per
// wave; compiler inserts lgkmcnt waits for the aliasing write->read deps).
// Removing __syncthreads() decouples the 4 waves: no wave waits on another's
// straggler row-degree (max-of-64 -> max-of-16) and no vmcnt(0) drains.
template <int WITH_MSG>
__global__ void __launch_bounds__(256) pass_mfma_k(
    const int* __restrict__ row_ptr, const unsigned* __restrict__ adj,
    const float* __restrict__ degi, const unsigned short* __restrict__ MSGsrc,
    const unsigned short* __restrict__ NODEb,
    const unsigned short* __restrict__ gWp, const unsigned short* __restrict__ uW1p,
    const unsigned short* __restrict__ uW2p, const float* __restrict__ gB,
    const float* __restrict__ uB1, const float* __restrict__ uB2,
    const float* __restrict__ LNG, const float* __restrict__ LNB,
    const unsigned short* __restrict__ mWp,  // next layer msg W1|W2 (packed)
    const float* __restrict__ mB1, const float* __restrict__ mB2,
    float* __restrict__ OUTf, unsigned short* __restrict__ OUTb,
    unsigned short* __restrict__ MSGdst, int base, int N) {
  __shared__ unsigned short lds[4][16 * 72];
  const int wave = threadIdx.x >> 6, l = threadIdx.x & 63;
  const int col = l & 15, quad = l >> 4;
  const int n0_raw = blockIdx.x * 64 + wave * 16;
  const bool dead = n0_raw >= N;
  const int n0 = dead ? 0 : n0_raw;

  // ---- phase 1: aggregate (in-register A-frag build) ----
  const int r = base + n0 + col;
  const int ps = row_ptr[r], pe = row_ptr[r + 1];
  float acc0[8], acc1[8];
#pragma unroll
  for (int j = 0; j < 8; ++j) { acc0[j] = 0.0f; acc1[j] = 0.0f; }
  int p = ps;
  for (; p + 4 <= pe; p += 4) {  // x4 unroll: 8 gathers in flight per lane
    unsigned av[4];
#pragma unroll
    for (int j = 0; j < 4; ++j) av[j] = adj[p + j];
    bf16x8 m0[4], m1[4];
#pragma unroll
    for (int j = 0; j < 4; ++j) {
      const unsigned short* m = MSGsrc + (size_t)(av[j] >> 14) * 64 + quad * 8;
      m0[j] = *(const bf16x8*)m;
      m1[j] = *(const bf16x8*)(m + 32);
    }
#pragma unroll
    for (int j = 0; j < 4; ++j) {
      const float w = (float)(av[j] & 16383u) * WQ_INV;
      const unsigned* u0 = (const unsigned*)&m0[j];
      const unsigned* u1 = (const unsigned*)&m1[j];
#pragma unroll
      for (int q = 0; q < 4; ++q) {
        acc0[2 * q] = fmaf(__uint_as_float(u0[q] << 16), w, acc0[2 * q]);
        acc0[2 * q + 1] = fmaf(__uint_as_float(u0[q] & 0xffff0000u), w, acc0[2 * q + 1]);
        acc1[2 * q] = fmaf(__uint_as_float(u1[q] << 16), w, acc1[2 * q]);
        acc1[2 * q + 1] = fmaf(__uint_as_float(u1[q] & 0xffff0000u), w, acc1[2 * q + 1]);
      }
    }
  }
  for (; p + 2 <= pe; p += 2) {  // x2 tail
    const unsigned avA = adj[p], avB = adj[p + 1];
    const unsigned short* mA = MSGsrc + (size_t)(avA >> 14) * 64 + quad * 8;
    const unsigned short* mB = MSGsrc + (size_t)(avB >> 14) * 64 + quad * 8;
    const bf16x8 mA0 = *(const bf16x8*)mA;
    const bf16x8 mA1 = *(const bf16x8*)(mA + 32);
    const bf16x8 mB0 = *(const bf16x8*)mB;
    const bf16x8 mB1v = *(const bf16x8*)(mB + 32);
    const float wA = (float)(avA & 16383u) * WQ_INV;
    const float wB = (float)(avB & 16383u) * WQ_INV;
    const unsigned* uA0 = (const unsigned*)&mA0;
    const unsigned* uA1 = (const unsigned*)&mA1;
    const unsigned* uB0 = (const unsigned*)&mB0;
    const unsigned* uB1v = (const unsigned*)&mB1v;
#pragma unroll
    for (int q = 0; q < 4; ++q) {
      acc0[2 * q] = fmaf(__uint_as_float(uA0[q] << 16), wA, acc0[2 * q]);
      acc0[2 * q + 1] = fmaf(__uint_as_float(uA0[q] & 0xffff0000u), wA, acc0[2 * q + 1]);
      acc1[2 * q] = fmaf(__uint_as_float(uA1[q] << 16), wA, acc1[2 * q]);
      acc1[2 * q + 1] = fmaf(__uint_as_float(uA1[q] & 0xffff0000u), wA, acc1[2 * q + 1]);
      acc0[2 * q] = fmaf(__uint_as_float(uB0[q] << 16), wB, acc0[2 * q]);
      acc0[2 * q + 1] = fmaf(__uint_as_float(uB0[q] & 0xffff0000u), wB, acc0[2 * q + 1]);
      acc1[2 * q] = fmaf(__uint_as_float(uB1v[q] << 16), wB, acc1[2 * q]);
      acc1[2 * q + 1] = fmaf(__uint_as_float(uB1v[q] & 0xffff0000u), wB, acc1[2 * q + 1]);
    }
  }
  if (p < pe) {
    const unsigned av = adj[p];
    const unsigned short* m = MSGsrc + (size_t)(av >> 14) * 64 + quad * 8;
    const bf16x8 m0 = *(const bf16x8*)m;
    const bf16x8 m1 = *(const bf16x8*)(m + 32);
    const float w = (float)(av & 16383u) * WQ_INV;
    const unsigned* u0 = (const unsigned*)&m0;
    const unsigned* u1 = (const unsigned*)&m1;
#pragma unroll
    for (int q = 0; q < 4; ++q) {
      acc0[2 * q] = fmaf(__uint_as_float(u0[q] << 16), w, acc0[2 * q]);
      acc0[2 * q + 1] = fmaf(__uint_as_float(u0[q] & 0xffff0000u), w, acc0[2 * q + 1]);
      acc1[2 * q] = fmaf(__uint_as_float(u1[q] << 16), w, acc1[2 * q]);
      acc1[2 * q + 1] = fmaf(__uint_as_float(u1[q] & 0xffff0000u), w, acc1[2 * q + 1]);
    }
  }
  const float di = degi[r];
  bf16x8 aA0, aA1;
#pragma unroll
  for (int j = 0; j < 8; ++j) {
    aA0[j] = (short)f2bf(acc0[j] * di);
    aA1[j] = (short)f2bf(acc1[j] * di);
  }

  // ---- phase 2: gate + upd1 (MFMA) ----
  const unsigned short* nrow = NODEb + (size_t)(n0 + col) * 64 + quad * 8;
  const bf16x8 aN0 = *(const bf16x8*)nrow;
  const bf16x8 aN1 = *(const bf16x8*)(nrow + 32);
  const bf16x8* gW = (const bf16x8*)gWp;
  const bf16x8* uW1 = (const bf16x8*)uW1p;
  const bf16x8* uW2 = (const bf16x8*)uW2p;

  f32x4 g[4], u[4];
#pragma unroll
  for (int t = 0; t < 4; ++t) {
    const float bg = gB[col + 16 * t], bu = uB1[col + 16 * t];
    g[t] = f32x4{bg, bg, bg, bg};
    u[t] = f32x4{bu, bu, bu, bu};
  }
#pragma unroll
  for (int t = 0; t < 4; ++t) {
    g[t] = __builtin_amdgcn_mfma_f32_16x16x32_bf16(aA0, gW[t * 64 + l], g[t], 0, 0, 0);
    g[t] = __builtin_amdgcn_mfma_f32_16x16x32_bf16(aA1, gW[(4 + t) * 64 + l], g[t], 0, 0, 0);
    g[t] = __builtin_amdgcn_mfma_f32_16x16x32_bf16(aN0, gW[(8 + t) * 64 + l], g[t], 0, 0, 0);
    g[t] = __builtin_amdgcn_mfma_f32_16x16x32_bf16(aN1, gW[(12 + t) * 64 + l], g[t], 0, 0, 0);
    u[t] = __builtin_amdgcn_mfma_f32_16x16x32_bf16(aA0, uW1[t * 64 + l], u[t], 0, 0, 0);
    u[t] = __builtin_amdgcn_mfma_f32_16x16x32_bf16(aA1, uW1[(4 + t) * 64 + l], u[t], 0, 0, 0);
    u[t] = __builtin_amdgcn_mfma_f32_16x16x32_bf16(aN0, uW1[(8 + t) * 64 + l], u[t], 0, 0, 0);
    u[t] = __builtin_amdgcn_mfma_f32_16x16x32_bf16(aN1, uW1[(12 + t) * 64 + l], u[t], 0, 0, 0);
  }
#pragma unroll
  for (int t = 0; t < 4; ++t)
#pragma unroll
    for (int r2 = 0; r2 < 4; ++r2) g[t][r2] = sigmoid_f(g[t][r2]);

  unsigned short* ld = lds[wave];
#pragma unroll
  for (int t = 0; t < 4; ++t)
#pragma unroll
    for (int r2 = 0; r2 < 4; ++r2)
      ld[(quad * 4 + r2) * 72 + col + 16 * t] = f2bf(fmaxf(u[t][r2], 0.0f));
  // no barrier: per-wave LDS slice, in-order ds ops within the wave
  const bf16x8 h0 = *(const bf16x8*)&ld[col * 72 + quad * 8];
  const bf16x8 h1 = *(const bf16x8*)&ld[col * 72 + 32 + quad * 8];
  f32x4 o[4];
#pragma unroll
  for (int t = 0; t < 4; ++t) {
    const float b = uB2[col + 16 * t];
    o[t] = f32x4{b, b, b, b};
  }
#pragma unroll
  for (int t = 0; t < 4; ++t) {
    o[t] = __builtin_amdgcn_mfma_f32_16x16x32_bf16(h0, uW2[t * 64 + l], o[t], 0, 0, 0);
    o[t] = __builtin_amdgcn_mfma_f32_16x16x32_bf16(h1, uW2[(4 + t) * 64 + l], o[t], 0, 0, 0);
  }
  // gate mix (bf16 node carry, C-layout gather) + LayerNorm
  float om[4][4];
#pragma unroll
  for (int t = 0; t < 4; ++t)
#pragma unroll
    for (int r2 = 0; r2 < 4; ++r2) {
      const float nd =
          bf2f(NODEb[(size_t)(n0 + quad * 4 + r2) * 64 + col + 16 * t]);
      om[t][r2] = fmaf(g[t][r2], o[t][r2] - nd, nd);
    }
  float outv[4][4];
#pragma unroll
  for (int r2 = 0; r2 < 4; ++r2) {
    float s1 = (om[0][r2] + om[1][r2]) + (om[2][r2] + om[3][r2]);
    float s2 = fmaf(om[0][r2], om[0][r2], fmaf(om[1][r2], om[1][r2],
                fmaf(om[2][r2], om[2][r2], om[3][r2] * om[3][r2])));
#pragma unroll
    for (int off = 1; off < 16; off <<= 1) {
      s1 += __shfl_xor(s1, off, 64);
      s2 += __shfl_xor(s2, off, 64);
    }
    const float m = s1 * (1.0f / 64.0f);
    const float var = s2 * (1.0f / 64.0f) - m * m;
    const float rr = rsqrtf(var + 1e-3f);
#pragma unroll
    for (int t = 0; t < 4; ++t)
      outv[t][r2] = fmaf((om[t][r2] - m) * rr, LNG[col + 16 * t], LNB[col + 16 * t]);
  }
  if (OUTf != nullptr && !dead) {
#pragma unroll
    for (int t = 0; t < 4; ++t)
#pragma unroll
      for (int r2 = 0; r2 < 4; ++r2)
        OUTf[(size_t)(n0 + quad * 4 + r2) * 64 + col + 16 * t] = outv[t][r2];
  }
  // no barrier (WAR on ld is ordered by per-wave in-order ds ops)
#pragma unroll
  for (int t = 0; t < 4; ++t)
#pragma unroll
    for (int r2 = 0; r2 < 4; ++r2)
      ld[(quad * 4 + r2) * 72 + col + 16 * t] = f2bf(outv[t][r2]);
  // no barrier
  if (OUTb != nullptr && !dead) {
#pragma unroll
    for (int cc = 0; cc < 2; ++cc) {
      const bf16x8 v = *(const bf16x8*)&ld[col * 72 + (quad * 2 + cc) * 8];
      *(bf16x8*)(OUTb + (size_t)(n0 + col) * 64 + (quad * 2 + cc) * 8) = v;
    }
  }

  if constexpr (WITH_MSG) {
    // ---- phase 3: next layer's message MLP on the just-updated rows ----
    const bf16x8 x0 = *(const bf16x8*)&ld[col * 72 + quad * 8];
    const bf16x8 x1 = *(const bf16x8*)&ld[col * 72 + 32 + quad * 8];
    const bf16x8* W1p = (const bf16x8*)mWp;
    const bf16x8* W2p = (const bf16x8*)(mWp + 4096);
    f32x4 macc[4];
#pragma unroll
    for (int t = 0; t < 4; ++t) {
      const float b = mB1[col + 16 * t];
      macc[t] = f32x4{b, b, b, b};
    }
#pragma unroll
    for (int t = 0; t < 4; ++t) {
      macc[t] = __builtin_amdgcn_mfma_f32_16x16x32_bf16(x0, W1p[t * 64 + l], macc[t], 0, 0, 0);
      macc[t] = __builtin_amdgcn_mfma_f32_16x16x32_bf16(x1, W1p[(4 + t) * 64 + l], macc[t], 0, 0, 0);
    }
    // no barrier
#pragma unroll
    for (int t = 0; t < 4; ++t)
#pragma unroll
      for (int r2 = 0; r2 < 4; ++r2)
        ld[(quad * 4 + r2) * 72 + col + 16 * t] = f2bf(fmaxf(macc[t][r2], 0.0f));
    // no barrier
    const bf16x8 mh0 = *(const bf16x8*)&ld[col * 72 + quad * 8];
    const bf16x8 mh1 = *(const bf16x8*)&ld[col * 72 + 32 + quad * 8];
    f32x4 mo[4];
#pragma unroll
    for (int t = 0; t < 4; ++t) {
      const float b = mB2[col + 16 * t];
      mo[t] = f32x4{b, b, b, b};
    }
#pragma unroll
    for (int t = 0; t < 4; ++t) {
      mo[t] = __builtin_amdgcn_mfma_f32_16x16x32_bf16(mh0, W2p[t * 64 + l], mo[t], 0, 0, 0);
      mo[t] = __builtin_amdgcn_mfma_f32_16x16x32_bf16(mh1, W2p[(4 + t) * 64 + l], mo[t], 0, 0, 0);
    }
    // no barrier
#pragma unroll
    for (int t = 0; t < 4; ++t)
#pragma unroll
      for (int r2 = 0; r2 < 4; ++r2)
        ld[(quad * 4 + r2) * 72 + col + 16 * t] = f2bf(mo[t][r2]);
    // no barrier
    if (!dead) {
#pragma unroll
      for (int cc = 0; cc < 2; ++cc) {
        const bf16x8 v = *(const bf16x8*)&ld[col * 72 + (quad * 2 + cc) * 8];
        *(bf16x8*)(MSGdst + (size_t)(n0 + col) * 64 + (quad * 2 + cc) * 8) = v;
      }
    }
  }
}

// ===== edge weight + degree count w/ captured slot index (atomic return) =====
__global__ void __launch_bounds__(256) edgew_k(
    const int* __restrict__ S, const int* __restrict__ D,
    const float* __restrict__ EFX, const unsigned short* __restrict__ PA,
    const unsigned short* __restrict__ PB, const float* __restrict__ W1C,
    const float* __restrict__ W2, const float* __restrict__ B2,
    unsigned long long* __restrict__ stagedD,
    unsigned long long* __restrict__ stagedS,
    int* __restrict__ counts, int baseD, int baseS, int E) {
  const int l = threadIdx.x & 63;
  const int g = l >> 3, c = l & 7;
  float wc[8][8];
#pragma unroll
  for (int i = 0; i < 8; ++i) {
    const float4 v0 = *(const float4*)(W1C + i * 64 + c * 8);
    const float4 v1 = *(const float4*)(W1C + i * 64 + c * 8 + 4);
    wc[i][0] = v0.x; wc[i][1] = v0.y; wc[i][2] = v0.z; wc[i][3] = v0.w;
    wc[i][4] = v1.x; wc[i][5] = v1.y; wc[i][6] = v1.z; wc[i][7] = v1.w;
  }
  float w2c[8];
  {
    const float4 a0 = *(const float4*)(W2 + c * 8);
    const float4 a1 = *(const float4*)(W2 + c * 8 + 4);
    w2c[0] = a0.x; w2c[1] = a0.y; w2c[2] = a0.z; w2c[3] = a0.w;
    w2c[4] = a1.x; w2c[5] = a1.y; w2c[6] = a1.z; w2c[7] = a1.w;
  }
  const float b2 = B2[0];
  const int wave_id = blockIdx.x * 4 + (threadIdx.x >> 6);
  const int nwaves = gridDim.x * 4;
  for (int t0 = wave_id * 8; t0 < E; t0 += nwaves * 8) {
    const int e = t0 + g;
    const bool ok = e < E;
    const int ee = ok ? e : E - 1;
    const int s = __builtin_nontemporal_load(S + ee);
    const int d = __builtin_nontemporal_load(D + ee);
    // issue slot-index atomics EARLY; latency hides under the MLP below
    int kd = 0, ks = 0;
    const int rd = baseD + d, rs = baseS + s;
    if (ok && c == 0) {
      kd = atomicAdd(&counts[rd], 1);
      ks = atomicAdd(&counts[rs], 1);
    }
    const bf16x8 pa = *(const bf16x8*)(PA + (size_t)s * 64 + c * 8);
    const bf16x8 pb = *(const bf16x8*)(PB + (size_t)d * 64 + c * 8);
    const f32x4 ef0 =
        __builtin_nontemporal_load((const f32x4*)(EFX + (size_t)ee * 8));
    const f32x4 ef1 =
        __builtin_nontemporal_load((const f32x4*)(EFX + (size_t)ee * 8 + 4));
    const unsigned* pau = (const unsigned*)&pa;
    const unsigned* pbu = (const unsigned*)&pb;
    float h[8];
#pragma unroll
    for (int q = 0; q < 4; ++q) {
      h[2 * q] = __uint_as_float(pau[q] << 16) + __uint_as_float(pbu[q] << 16);
      h[2 * q + 1] = __uint_as_float(pau[q] & 0xffff0000u) +
                     __uint_as_float(pbu[q] & 0xffff0000u);
    }
    const float ef[8] = {ef0[0], ef0[1], ef0[2], ef0[3],
                         ef1[0], ef1[1], ef1[2], ef1[3]};
#pragma unroll
    for (int i = 0; i < 8; ++i)
#pragma unroll
      for (int j = 0; j < 8; ++j) h[j] = fmaf(ef[i], wc[i][j], h[j]);
    float t = 0.0f;
#pragma unroll
    for (int j = 0; j < 8; ++j) t = fmaf(fmaxf(h[j], 0.0f), w2c[j], t);
#pragma unroll
    for (int off = 1; off < 8; off <<= 1) t += __shfl_xor(t, off, 64);
    if (ok && c == 0) {
      const float w = sigmoid_f(t + b2);
      const unsigned w14 = (unsigned)(w * WQ_SCALE + 0.5f);
      stagedD[e] =
          (unsigned long long)((unsigned)rd | ((unsigned)kd << 19)) |
          ((unsigned long long)(((unsigned)s << 14) | w14) << 32);
      stagedS[e] =
          (unsigned long long)((unsigned)rs | ((unsigned)ks << 19)) |
          ((unsigned long long)(((unsigned)d << 14) | w14) << 32);
    }
  }
}

// ==== atomic-free CSR fill: bin=blockIdx&7 pins a row range to one XCD =====
__global__ void __launch_bounds__(256) fill_staged_k(
    const unsigned long long* __restrict__ staged,
    const int* __restrict__ row_ptr, unsigned* __restrict__ adj) {
  const int bin = blockIdx.x & 7;
  const int blk = blockIdx.x >> 3;
  const int nblk = gridDim.x >> 3;
  const int lo = (bin == 0) ? 0 : c_bin_hi[bin - 1];
  const int hi = c_bin_hi[bin];
  const int slo = c_seg_lo[bin], shi = c_seg_hi[bin];
  for (int i = slo + blk * 256 + threadIdx.x; i < shi; i += nblk * 256) {
    const unsigned long long v = __builtin_nontemporal_load(staged + i);
    const int row = (int)(v & 0x7ffffull);
    if (row >= lo && row < hi) {
      const int k = (int)((v >> 19) & 0x1fffull);
      adj[row_ptr[row] + k] = (unsigned)(v >> 32);
    }
  }
}

__global__ void __launch_bounds__(256) degi_k(const int* __restrict__ row_ptr,
                                             const unsigned* __restrict__ adj,
                                             float* __restrict__ degi) {
  const int r = blockIdx.x * 256 + threadIdx.x;
  if (r >= R_TOT) return;
  const int s = row_ptr[r], e = row_ptr[r + 1];
  float d = 0.0f;
  for (int p = s; p < e; ++p) d += (float)(adj[p] & 16383u) * WQ_INV;
  degi[r] = 1.0f / fmaxf(d, 1.0f);
}

__global__ void __launch_bounds__(256) scan1_k(const int* __restrict__ in,
                                               int* __restrict__ bsum) {
  __shared__ int sd[256];
  const int t = threadIdx.x;
  const int base = blockIdx.x * SCAN_CHUNK + t * 8;
  int s = 0;
#pragma unroll
  for (int i = 0; i < 8; ++i) {
    const int idx = base + i;
    s += (idx < R_TOT) ? in[idx] : 0;
  }
  sd[t] = s;
  __syncthreads();
  for (int off = 128; off > 0; off >>= 1) {
    if (t < off) sd[t] += sd[t + off];
    __syncthreads();
  }
  if (t == 0) bsum[blockIdx.x] = sd[0];
}

__global__ void __launch_bounds__(256) scan2_k(int* __restrict__ bsum,
                                               int* __restrict__ row_ptr) {
  __shared__ int sd[256];
  const int t = threadIdx.x;
  const int v = (t < SCAN_NB) ? bsum[t] : 0;
  sd[t] = v;
  __syncthreads();
  for (int off = 1; off < 256; off <<= 1) {
    const int add = (t >= off) ? sd[t - off] : 0;
    __syncthreads();
    sd[t] += add;
    __syncthreads();
  }
  if (t < SCAN_NB) bsum[t] = sd[t] - v;
  if (t == 255) row_ptr[R_TOT] = sd[255];
}

__global__ void __launch_bounds__(256) scan3_k(const int* __restrict__ in,
                                               const int* __restrict__ bsum,
                                               int* __restrict__ out) {
  __shared__ int sd[256];
  const int t = threadIdx.x;
  const int base = blockIdx.x * SCAN_CHUNK + t * 8;
  int loc[8];
  int s = 0;
#pragma unroll
  for (int i = 0; i < 8; ++i) {
    loc[i] = s;
    const int idx = base + i;
    s += (idx < R_TOT) ? in[idx] : 0;
  }
  sd[t] = s;
  __syncthreads();
  const int v = s;
  for (int off = 1; off < 256; off <<= 1) {
    const int add = (t >= off) ? sd[t - off] : 0;
    __syncthreads();
    sd[t] += add;
    __syncthreads();
  }
  const int off0 = bsum[blockIdx.x] + (sd[t] - v);
#pragma unroll
  for (int i = 0; i < 8; ++i) {
    const int idx = base + i;
    if (idx < R_TOT) out[idx] = off0 + loc[i];
  }
}

}  // namespace

extern "C" void kernel_launch(void* const* d_in, const int* in_sizes, int n_in,
                              void* d_out, int out_size, void* d_ws, size_t ws_size,
                              hipStream_t stream) {
  (void)in_sizes; (void)n_in; (void)out_size; (void)ws_size;

  const float* variable_features   = (const float*)d_in[0];
  const float* constraint_features = (const float*)d_in[1];
  const float* cut_features        = (const float*)d_in[2];
  const float* vc_ef = (const float*)d_in[3];
  const float* vk_ef = (const float*)d_in[4];
  const int* vc_edges = (const int*)d_in[5];
  const int* vk_edges = (const int*)d_in[6];
  const int *vc_s = vc_edges, *vc_d = vc_edges + EVC;
  const int *vk_s = vk_edges, *vk_d = vk_edges + EVK;
  const float* var_w1  = (const float*)d_in[7];
  const float* var_b1  = (const float*)d_in[8];
  const float* var_w2  = (const float*)d_in[9];
  const float* var_b2  = (const float*)d_in[10];
  const float* cons_w1 = (const float*)d_in[11];
  const float* cons_b1 = (const float*)d_in[12];
  const float* cons_w2 = (const float*)d_in[13];
  const float* cons_b2 = (const float*)d_in[14];
  const float* cut_w1  = (const float*)d_in[15];
  const float* cut_b1  = (const float*)d_in[16];
  const float* cut_w2  = (const float*)d_in[17];
  const float* cut_b2  = (const float*)d_in[18];
  const float* ewvc_w1 = (const float*)d_in[19];
  const float* ewvc_b1 = (const float*)d_in[20];
  const float* ewvc_w2 = (const float*)d_in[21];
  const float* ewvc_b2 = (const float*)d_in[22];
  const float* ewvk_w1 = (const float*)d_in[23];
  const float* ewvk_b1 = (const float*)d_in[24];
  const float* ewvk_w2 = (const float*)d_in[25];
  const float* ewvk_b2 = (const float*)d_in[26];
  const float* mp_msg_w1 = (const float*)d_in[27];
  const float* mp_msg_b1 = (const float*)d_in[28];
  const float* mp_msg_w2 = (const float*)d_in[29];
  const float* mp_msg_b2 = (const float*)d_in[30];
  const float* mp_gate_w = (const float*)d_in[31];
  const float* mp_gate_b = (const float*)d_in[32];
  const float* mp_upd_w1 = (const float*)d_in[33];
  const float* mp_upd_b1 = (const float*)d_in[34];
  const float* mp_upd_w2 = (const float*)d_in[35];
  const float* mp_upd_b2 = (const float*)d_in[36];
  const float* mp_ln_g   = (const float*)d_in[37];
  const float* mp_ln_b   = (const float*)d_in[38];

  // ---- workspace carve ----
  char* wp = (char*)d_ws;
  auto take = [&](size_t nbytes) {
    char* p = wp;
    wp += (nbytes + 255) & ~(size_t)255;
    return p;
  };
  unsigned short* h_var_b  = (unsigned short*)take((size_t)NV * 64 * 2);
  unsigned short* h_cons_b = (unsigned short*)take((size_t)NC * 64 * 2);
  unsigned short* h_cut_b  = (unsigned short*)take((size_t)NK * 64 * 2);
  unsigned short* msg_ping = (unsigned short*)take((size_t)NV * 64 * 2);
  unsigned short* msg_pong = (unsigned short*)take((size_t)NV * 64 * 2);
  unsigned short* pa = (unsigned short*)take((size_t)NV * 64 * 2);
  unsigned short* pb = (unsigned short*)take((size_t)NC * 64 * 2);
  unsigned short* qa = (unsigned short*)take((size_t)NV * 64 * 2);
  unsigned short* qb = (unsigned short*)take((size_t)NK * 64 * 2);
  unsigned short* packW = (unsigned short*)take((size_t)15 * PACK_PER_LAYER * 2);
  unsigned short* packE = (unsigned short*)take((size_t)PE_TOTAL * 2);
  int* row_ptr = (int*)take((size_t)(R_TOT + 1) * 4);
  int* counts  = (int*)take((size_t)R_TOT * 4);
  int* bsum    = (int*)take(256 * 4);
  float* degi  = (float*)take((size_t)R_TOT * 4);
  unsigned* adj = (unsigned*)take((size_t)(2 * EVC + 2 * EVK) * 4);

  // ---- time-sliced alias (no extra workspace) ----
  // staged pairs (16MB, live: edgew -> fill_staged) alias msg ping+pong
  // (25.6MB, first written by msg_mfma_k long after fill completes).
  unsigned long long* staged = (unsigned long long*)msg_ping;

  // ---- init counts (filled during edgew) ----
  hipMemsetAsync(counts, 0, (size_t)R_TOT * 4, stream);

  // ---- pack weights (MP layers + embeddings/edge-weight mats) ----
  pack_k<<<15, 256, 0, stream>>>(mp_msg_w1, mp_msg_w2, mp_gate_w, mp_upd_w1,
                                 mp_upd_w2, packW);
  pack_emb_k<<<10, 256, 0, stream>>>(var_w1, var_w2, cons_w1, cons_w2, cut_w1,
                                     cut_w2, ewvc_w1, ewvk_w1, packE);

  // ---- embeddings (MFMA, bf16 out) ----
  emb_mfma_k<19><<<(NV + 63) / 64, 256, 0, stream>>>(
      variable_features, packE + PE_VAR_W1, packE + PE_VAR_W2, var_b1, var_b2,
      h_var_b, NV);
  emb_mfma_k<5><<<(NC + 63) / 64, 256, 0, stream>>>(
      constraint_features, packE + PE_CONS_W1, packE + PE_CONS_W2, cons_b1,
      cons_b2, h_cons_b, NC);
  emb_mfma_k<30><<<(NK + 63) / 64, 256, 0, stream>>>(
      cut_features, packE + PE_CUT_W1, packE + PE_CUT_W2, cut_b1, cut_b2,
      h_cut_b, NK);

  // ---- edge-weight per-node terms (MFMA; var does both projections) ----
  gemv_mfma_k<2><<<(NV + 63) / 64, 256, 0, stream>>>(
      h_var_b, packE + PE_EWVC_A, packE + PE_EWVK_A, nullptr, pa, qa, NV);
  gemv_mfma_k<1><<<(NC + 63) / 64, 256, 0, stream>>>(
      h_cons_b, packE + PE_EWVC_B, nullptr, ewvc_b1, pb, nullptr, NC);
  gemv_mfma_k<1><<<(NK + 63) / 64, 256, 0, stream>>>(
      h_cut_b, packE + PE_EWVK_B, nullptr, ewvk_b1, qb, nullptr, NK);

  // ---- edge weights + degree counts (atomic-return = CSR slot index) ----
  edgew_k<<<1024, 256, 0, stream>>>(vc_s, vc_d, vc_ef, pa, pb,
                                    ewvc_w1 + 128 * 64, ewvc_w2, ewvc_b2,
                                    staged, staged + EVC, counts, 0, NC, EVC);
  edgew_k<<<512, 256, 0, stream>>>(vk_s, vk_d, vk_ef, qa, qb,
                                   ewvk_w1 + 128 * 64, ewvk_w2, ewvk_b2,
                                   staged + 2 * EVC, staged + 2 * EVC + EVK,
                                   counts, NC + NV, NC + NV + NK, EVK);

  // ---- CSR scan + atomic-free XCD-local fill + 1/deg ----
  scan1_k<<<SCAN_NB, 256, 0, stream>>>(counts, bsum);
  scan2_k<<<1, 256, 0, stream>>>(bsum, row_ptr);
  scan3_k<<<SCAN_NB, 256, 0, stream>>>(counts, bsum, row_ptr);
  fill_staged_k<<<8 * 192, 256, 0, stream>>>(staged, row_ptr, adj);
  degi_k<<<(R_TOT + 255) / 256, 256, 0, stream>>>(row_ptr, adj, degi);

  // ---- 15 fully-fused passes (agg + upd + next msg), msg ping-pong ----
  unsigned short* nodeb_t[4] = {h_cons_b, h_var_b, h_cut_b, h_var_b};
  const int Nd_t[4] = {NC, NV, NK, NV};
  const int base_t[4] = {0, NC, NC + NV, NC + NV + NK};

  // msg(0): over h_var with layer-0 msg weights -> ping
  msg_mfma_k<<<(NV + 63) / 64, 256, 0, stream>>>(
      h_var_b, packW, mp_msg_b1, mp_msg_b2, msg_ping, NV);

  for (int i = 0; i < 15; ++i) {
    const int d = i & 3;
    const int Nd = Nd_t[d], base = base_t[d];
    const unsigned short* Wl = packW + (size_t)i * PACK_PER_LAYER;
    const unsigned short* src = (i % 2 == 0) ? msg_ping : msg_pong;
    unsigned short* dst = (i % 2 == 0) ? msg_pong : msg_ping;

    if (i < 14) {
      const unsigned short* Wn = packW + (size_t)(i + 1) * PACK_PER_LAYER;
      pass_mfma_k<1><<<(Nd + 63) / 64, 256, 0, stream>>>(
          row_ptr, adj, degi, src, nodeb_t[d], Wl + 8192, Wl + 16384,
          Wl + 24576, mp_gate_b + (size_t)i * 64, mp_upd_b1 + (size_t)i * 64,
          mp_upd_b2 + (size_t)i * 64, mp_ln_g + (size_t)i * 64,
          mp_ln_b + (size_t)i * 64, Wn, mp_msg_b1 + (size_t)(i + 1) * 64,
          mp_msg_b2 + (size_t)(i + 1) * 64, nullptr, nodeb_t[d], dst, base, Nd);
    } else {
      pass_mfma_k<0><<<(Nd + 63) / 64, 256, 0, stream>>>(
          row_ptr, adj, degi, src, nodeb_t[d], Wl + 8192, Wl + 16384,
          Wl + 24576, mp_gate_b + (size_t)i * 64, mp_upd_b1 + (size_t)i * 64,
          mp_upd_b2 + (size_t)i * 64, mp_ln_g + (size_t)i * 64,
          mp_ln_b + (size_t)i * 64, nullptr, nullptr, nullptr,
          (float*)d_out, nullptr, nullptr, base, Nd);
    }
  }
}

// Round 10
// 774.462 us; speedup vs baseline: 1.7828x; 1.0334x over previous
//
#include <hip/hip_runtime.h>

#define DEVINL static __device__ __forceinline__

namespace {

typedef __attribute__((ext_vector_type(8))) short bf16x8;
typedef __attribute__((ext_vector_type(4))) float f32x4;

constexpr int NV = 100000;   // variables
constexpr int NC = 50000;    // constraints
constexpr int NK = 20000;    // cuts
constexpr int EVC = 800000;  // var-cons edges
constexpr int EVK = 200000;  // var-cut edges
constexpr int E_TOT2 = 2 * (EVC + EVK);  // 2M staged entries
constexpr int R_TOT = NC + NV + NK + NV;  // 270000 CSR rows
constexpr int SCAN_CHUNK = 2048;
constexpr int SCAN_NB = (R_TOT + SCAN_CHUNK - 1) / SCAN_CHUNK;  // 132
constexpr int PACK_PER_LAYER = 28672;  // ushort per layer of packed MP weights
constexpr float WQ_SCALE = 16383.0f;
constexpr float WQ_INV = 1.0f / 16383.0f;

// merged-launch block partitions
constexpr int NB_EVC = 1024, NB_EVK = 512;           // edgew2_k
constexpr int NB_VAR = (NV + 63) / 64;               // 1563
constexpr int NB_CONS = (NC + 63) / 64;              // 782
constexpr int NB_CUT = (NK + 63) / 64;               // 313

// ---- atomic-free CSR fill: 8 row-range bins, XCD-pinned (blockIdx&7) ----
__constant__ int c_bin_hi[8] = {12500, 25000, 37500, 50000,
                                83334, 116667, 150000, 270000};
__constant__ int c_seg_lo[8] = {0, 0, 0, 0, EVC, EVC, EVC, 2 * EVC};
__constant__ int c_seg_hi[8] = {EVC, EVC, EVC, EVC,
                                2 * EVC, 2 * EVC, 2 * EVC, E_TOT2};

// packed embedding/edge-weight matrix offsets (ushort)
constexpr int PE_VAR_W1 = 0;      // Kpad=32 -> 2048
constexpr int PE_VAR_W2 = 2048;   // K=64   -> 4096
constexpr int PE_CONS_W1 = 6144;  // 2048
constexpr int PE_CONS_W2 = 8192;  // 4096
constexpr int PE_CUT_W1 = 12288;  // 2048
constexpr int PE_CUT_W2 = 14336;  // 4096
constexpr int PE_EWVC_A = 18432;  // 4096
constexpr int PE_EWVC_B = 22528;  // 4096
constexpr int PE_EWVK_A = 26624;  // 4096
constexpr int PE_EWVK_B = 30720;  // 4096
constexpr int PE_TOTAL = 34816;

DEVINL unsigned short f2bf(float f) {
  unsigned u = __float_as_uint(f);
  u = u + 0x7fffu + ((u >> 16) & 1u);  // RNE
  return (unsigned short)(u >> 16);
}
DEVINL float bf2f(unsigned short h) {
  return __uint_as_float((unsigned)h << 16);
}

DEVINL float sigmoid_f(float x) { return 1.0f / (1.0f + __expf(-x)); }

// ======================= weight packing (bf16 B-frag streams) ================
DEVINL void pack_mat(const float* __restrict__ src, int K, int Kpad,
                     unsigned short* __restrict__ dst, int tid) {
  const int ntup = (Kpad / 32) * 256;
  for (int tup = tid; tup < ntup; tup += 256) {
    const int lane = tup & 63;
    const int t = (tup >> 6) & 3;
    const int kb = tup >> 8;
    const int c = t * 16 + (lane & 15);
    const int k0 = kb * 32 + (lane >> 4) * 8;
#pragma unroll
    for (int jj = 0; jj < 8; ++jj)
      dst[tup * 8 + jj] =
          (k0 + jj < K) ? f2bf(src[(k0 + jj) * 64 + c]) : (unsigned short)0;
  }
}

__global__ void __launch_bounds__(256) pack_k(
    const float* __restrict__ mW1, const float* __restrict__ mW2,
    const float* __restrict__ gW, const float* __restrict__ uW1,
    const float* __restrict__ uW2, unsigned short* __restrict__ PW) {
  const int layer = blockIdx.x;  // 0..14
  unsigned short* out = PW + (size_t)layer * PACK_PER_LAYER;
  pack_mat(mW1 + (size_t)layer * 4096, 64, 64, out, threadIdx.x);
  pack_mat(mW2 + (size_t)layer * 4096, 64, 64, out + 4096, threadIdx.x);
  pack_mat(gW + (size_t)layer * 8192, 128, 128, out + 8192, threadIdx.x);
  pack_mat(uW1 + (size_t)layer * 8192, 128, 128, out + 16384, threadIdx.x);
  pack_mat(uW2 + (size_t)layer * 4096, 64, 64, out + 24576, threadIdx.x);
}

__global__ void __launch_bounds__(256) pack_emb_k(
    const float* __restrict__ var_w1, const float* __restrict__ var_w2,
    const float* __restrict__ cons_w1, const float* __restrict__ cons_w2,
    const float* __restrict__ cut_w1, const float* __restrict__ cut_w2,
    const float* __restrict__ ewvc_w1, const float* __restrict__ ewvk_w1,
    unsigned short* __restrict__ P) {
  switch (blockIdx.x) {
    case 0: pack_mat(var_w1, 19, 32, P + PE_VAR_W1, threadIdx.x); break;
    case 1: pack_mat(var_w2, 64, 64, P + PE_VAR_W2, threadIdx.x); break;
    case 2: pack_mat(cons_w1, 5, 32, P + PE_CONS_W1, threadIdx.x); break;
    case 3: pack_mat(cons_w2, 64, 64, P + PE_CONS_W2, threadIdx.x); break;
    case 4: pack_mat(cut_w1, 30, 32, P + PE_CUT_W1, threadIdx.x); break;
    case 5: pack_mat(cut_w2, 64, 64, P + PE_CUT_W2, threadIdx.x); break;
    case 6: pack_mat(ewvc_w1, 64, 64, P + PE_EWVC_A, threadIdx.x); break;
    case 7: pack_mat(ewvc_w1 + 64 * 64, 64, 64, P + PE_EWVC_B, threadIdx.x); break;
    case 8: pack_mat(ewvk_w1, 64, 64, P + PE_EWVK_A, threadIdx.x); break;
    case 9: pack_mat(ewvk_w1 + 64 * 64, 64, 64, P + PE_EWVK_B, threadIdx.x); break;
  }
}

// ======================= embedding MLP body (MFMA, K1 padded to 32) ==========
template <int DIN>
DEVINL void emb_body(const float* __restrict__ X,
                     const unsigned short* __restrict__ W1p_,
                     const unsigned short* __restrict__ W2p_,
                     const float* __restrict__ B1, const float* __restrict__ B2,
                     unsigned short* __restrict__ OUTb, int N, int bid,
                     unsigned short* __restrict__ ld) {
  const int l = threadIdx.x & 63;
  const int wave = threadIdx.x >> 6;
  const int col = l & 15, quad = l >> 4;
  const int n0_raw = bid * 64 + wave * 16;
  const bool dead = n0_raw >= N;
  const int n0 = dead ? 0 : n0_raw;

  bf16x8 a0;
#pragma unroll
  for (int j = 0; j < 8; ++j) {
    const int k = quad * 8 + j;
    a0[j] = (k < DIN) ? (short)f2bf(X[(size_t)(n0 + col) * DIN + k]) : (short)0;
  }
  const bf16x8* W1p = (const bf16x8*)W1p_;
  const bf16x8* W2p = (const bf16x8*)W2p_;
  f32x4 acc[4];
#pragma unroll
  for (int t = 0; t < 4; ++t) {
    const float b = B1[col + 16 * t];
    acc[t] = f32x4{b, b, b, b};
  }
#pragma unroll
  for (int t = 0; t < 4; ++t)
    acc[t] = __builtin_amdgcn_mfma_f32_16x16x32_bf16(a0, W1p[t * 64 + l], acc[t], 0, 0, 0);
#pragma unroll
  for (int t = 0; t < 4; ++t)
#pragma unroll
    for (int r = 0; r < 4; ++r)
      ld[(quad * 4 + r) * 72 + col + 16 * t] = f2bf(fmaxf(acc[t][r], 0.0f));
  // per-wave LDS slice; in-order ds ops within the wave (no barrier needed)
  const bf16x8 h0 = *(const bf16x8*)&ld[col * 72 + quad * 8];
  const bf16x8 h1 = *(const bf16x8*)&ld[col * 72 + 32 + quad * 8];
  f32x4 o[4];
#pragma unroll
  for (int t = 0; t < 4; ++t) {
    const float b = B2[col + 16 * t];
    o[t] = f32x4{b, b, b, b};
  }
#pragma unroll
  for (int t = 0; t < 4; ++t) {
    o[t] = __builtin_amdgcn_mfma_f32_16x16x32_bf16(h0, W2p[t * 64 + l], o[t], 0, 0, 0);
    o[t] = __builtin_amdgcn_mfma_f32_16x16x32_bf16(h1, W2p[(4 + t) * 64 + l], o[t], 0, 0, 0);
  }
#pragma unroll
  for (int t = 0; t < 4; ++t)
#pragma unroll
    for (int r = 0; r < 4; ++r)
      ld[(quad * 4 + r) * 72 + col + 16 * t] = f2bf(o[t][r]);
  if (!dead) {
#pragma unroll
    for (int cc = 0; cc < 2; ++cc) {
      const bf16x8 v = *(const bf16x8*)&ld[col * 72 + (quad * 2 + cc) * 8];
      *(bf16x8*)(OUTb + (size_t)(n0 + col) * 64 + (quad * 2 + cc) * 8) = v;
    }
  }
}

// merged: var | cons | cut embeddings in one dispatch (block-range select)
__global__ void __launch_bounds__(256) emb3_k(
    const float* __restrict__ Xv, const float* __restrict__ Xc,
    const float* __restrict__ Xk, const unsigned short* __restrict__ P,
    const float* __restrict__ vB1, const float* __restrict__ vB2,
    const float* __restrict__ cB1, const float* __restrict__ cB2,
    const float* __restrict__ kB1, const float* __restrict__ kB2,
    unsigned short* __restrict__ Ov, unsigned short* __restrict__ Oc,
    unsigned short* __restrict__ Ok) {
  __shared__ unsigned short lds[4][16 * 72];
  unsigned short* ld = lds[threadIdx.x >> 6];
  const int b = blockIdx.x;
  if (b < NB_VAR)
    emb_body<19>(Xv, P + PE_VAR_W1, P + PE_VAR_W2, vB1, vB2, Ov, NV, b, ld);
  else if (b < NB_VAR + NB_CONS)
    emb_body<5>(Xc, P + PE_CONS_W1, P + PE_CONS_W2, cB1, cB2, Oc, NC,
                b - NB_VAR, ld);
  else
    emb_body<30>(Xk, P + PE_CUT_W1, P + PE_CUT_W2, kB1, kB2, Ok, NK,
                 b - NB_VAR - NB_CONS, ld);
}

// ======= edge-weight per-node GEMV body (MFMA); NOUT=2 shares A-frag ========
template <int NOUT>
DEVINL void gemv_body(const unsigned short* __restrict__ Xb,
                      const unsigned short* __restrict__ WpA_,
                      const unsigned short* __restrict__ WpB_,
                      const float* __restrict__ Bias,
                      unsigned short* __restrict__ OUT0,
                      unsigned short* __restrict__ OUT1, int N, int bid,
                      unsigned short* __restrict__ ld) {
  const int l = threadIdx.x & 63;
  const int wave = threadIdx.x >> 6;
  const int col = l & 15, quad = l >> 4;
  const int n0_raw = bid * 64 + wave * 16;
  const bool dead = n0_raw >= N;
  const int n0 = dead ? 0 : n0_raw;
  const unsigned short* xrow = Xb + (size_t)(n0 + col) * 64 + quad * 8;
  const bf16x8 a0 = *(const bf16x8*)xrow;
  const bf16x8 a1 = *(const bf16x8*)(xrow + 32);
#pragma unroll
  for (int m = 0; m < NOUT; ++m) {
    const bf16x8* Wp = (const bf16x8*)(m == 0 ? WpA_ : WpB_);
    unsigned short* OUT = (m == 0) ? OUT0 : OUT1;
    f32x4 acc[4];
#pragma unroll
    for (int t = 0; t < 4; ++t) {
      const float b = (Bias != nullptr) ? Bias[col + 16 * t] : 0.0f;
      acc[t] = f32x4{b, b, b, b};
    }
#pragma unroll
    for (int t = 0; t < 4; ++t) {
      acc[t] = __builtin_amdgcn_mfma_f32_16x16x32_bf16(a0, Wp[t * 64 + l], acc[t], 0, 0, 0);
      acc[t] = __builtin_amdgcn_mfma_f32_16x16x32_bf16(a1, Wp[(4 + t) * 64 + l], acc[t], 0, 0, 0);
    }
#pragma unroll
    for (int t = 0; t < 4; ++t)
#pragma unroll
      for (int r = 0; r < 4; ++r)
        ld[(quad * 4 + r) * 72 + col + 16 * t] = f2bf(acc[t][r]);
    // per-wave slice, in-order ds ops
    if (!dead) {
#pragma unroll
      for (int cc = 0; cc < 2; ++cc) {
        const bf16x8 v = *(const bf16x8*)&ld[col * 72 + (quad * 2 + cc) * 8];
        *(bf16x8*)(OUT + (size_t)(n0 + col) * 64 + (quad * 2 + cc) * 8) = v;
      }
    }
  }
}

// merged: var(2-proj) | cons | cut edge-weight GEMVs in one dispatch
__global__ void __launch_bounds__(256) gemv3_k(
    const unsigned short* __restrict__ h_var,
    const unsigned short* __restrict__ h_cons,
    const unsigned short* __restrict__ h_cut,
    const unsigned short* __restrict__ P, const float* __restrict__ cBias,
    const float* __restrict__ kBias, unsigned short* __restrict__ pa,
    unsigned short* __restrict__ qa, unsigned short* __restrict__ pb,
    unsigned short* __restrict__ qb) {
  __shared__ unsigned short lds[4][16 * 72];
  unsigned short* ld = lds[threadIdx.x >> 6];
  const int b = blockIdx.x;
  if (b < NB_VAR)
    gemv_body<2>(h_var, P + PE_EWVC_A, P + PE_EWVK_A, nullptr, pa, qa, NV, b, ld);
  else if (b < NB_VAR + NB_CONS)
    gemv_body<1>(h_cons, P + PE_EWVC_B, nullptr, cBias, pb, nullptr, NC,
                 b - NB_VAR, ld);
  else
    gemv_body<1>(h_cut, P + PE_EWVK_B, nullptr, kBias, qb, nullptr, NK,
                 b - NB_VAR - NB_CONS, ld);
}

// ======================= message MLP (MFMA) — used once for pass 0 ===========
__global__ void __launch_bounds__(256) msg_mfma_k(
    const unsigned short* __restrict__ Xb, const unsigned short* __restrict__ Wp,
    const float* __restrict__ B1, const float* __restrict__ B2,
    unsigned short* __restrict__ MSGb, int N) {
  __shared__ unsigned short lds[4][16 * 72];
  const int wave = threadIdx.x >> 6, l = threadIdx.x & 63;
  const int col = l & 15, quad = l >> 4;
  const int n0_raw = blockIdx.x * 64 + wave * 16;
  const bool dead = n0_raw >= N;
  const int n0 = dead ? 0 : n0_raw;

  const unsigned short* xrow = Xb + (size_t)(n0 + col) * 64 + quad * 8;
  const bf16x8 a0 = *(const bf16x8*)xrow;
  const bf16x8 a1 = *(const bf16x8*)(xrow + 32);
  const bf16x8* W1p = (const bf16x8*)Wp;
  const bf16x8* W2p = (const bf16x8*)(Wp + 4096);

  f32x4 acc[4];
#pragma unroll
  for (int t = 0; t < 4; ++t) {
    const float b = B1[col + 16 * t];
    acc[t] = f32x4{b, b, b, b};
  }
#pragma unroll
  for (int t = 0; t < 4; ++t) {
    acc[t] = __builtin_amdgcn_mfma_f32_16x16x32_bf16(a0, W1p[t * 64 + l], acc[t], 0, 0, 0);
    acc[t] = __builtin_amdgcn_mfma_f32_16x16x32_bf16(a1, W1p[(4 + t) * 64 + l], acc[t], 0, 0, 0);
  }
  unsigned short* ld = lds[wave];
#pragma unroll
  for (int t = 0; t < 4; ++t)
#pragma unroll
    for (int r = 0; r < 4; ++r)
      ld[(quad * 4 + r) * 72 + col + 16 * t] = f2bf(fmaxf(acc[t][r], 0.0f));
  // per-wave slice, no barrier
  const bf16x8 h0 = *(const bf16x8*)&ld[col * 72 + quad * 8];
  const bf16x8 h1 = *(const bf16x8*)&ld[col * 72 + 32 + quad * 8];
  f32x4 o[4];
#pragma unroll
  for (int t = 0; t < 4; ++t) {
    const float b = B2[col + 16 * t];
    o[t] = f32x4{b, b, b, b};
  }
#pragma unroll
  for (int t = 0; t < 4; ++t) {
    o[t] = __builtin_amdgcn_mfma_f32_16x16x32_bf16(h0, W2p[t * 64 + l], o[t], 0, 0, 0);
    o[t] = __builtin_amdgcn_mfma_f32_16x16x32_bf16(h1, W2p[(4 + t) * 64 + l], o[t], 0, 0, 0);
  }
#pragma unroll
  for (int t = 0; t < 4; ++t)
#pragma unroll
    for (int r = 0; r < 4; ++r)
      ld[(quad * 4 + r) * 72 + col + 16 * t] = f2bf(o[t][r]);
  if (!dead) {
#pragma unroll
    for (int cc = 0; cc < 2; ++cc) {
      const bf16x8 v = *(const bf16x8*)&ld[col * 72 + (quad * 2 + cc) * 8];
      *(bf16x8*)(MSGb + (size_t)(n0 + col) * 64 + (quad * 2 + cc) * 8) = v;
    }
  }
}

// ==== fully-fused pass: CSR-aggregate + gate/upd/mix/LN + next-layer msg =====
// BARRIER-FREE (round-9 proven) + in-loop wsum (degi fused: removes the
// dependent degi[r] load from the aggregate->MFMA critical path and the
// separate degi_k kernel; identical summation order => same numerics).
template <int WITH_MSG>
__global__ void __launch_bounds__(256) pass_mfma_k(
    const int* __restrict__ row_ptr, const unsigned* __restrict__ adj,
    const unsigned short* __restrict__ MSGsrc,
    const unsigned short* __restrict__ NODEb,
    const unsigned short* __restrict__ gWp, const unsigned short* __restrict__ uW1p,
    const unsigned short* __restrict__ uW2p, const float* __restrict__ gB,
    const float* __restrict__ uB1, const float* __restrict__ uB2,
    const float* __restrict__ LNG, const float* __restrict__ LNB,
    const unsigned short* __restrict__ mWp,  // next layer msg W1|W2 (packed)
    const float* __restrict__ mB1, const float* __restrict__ mB2,
    float* __restrict__ OUTf, unsigned short* __restrict__ OUTb,
    unsigned short* __restrict__ MSGdst, int base, int N) {
  __shared__ unsigned short lds[4][16 * 72];
  const int wave = threadIdx.x >> 6, l = threadIdx.x & 63;
  const int col = l & 15, quad = l >> 4;
  const int n0_raw = blockIdx.x * 64 + wave * 16;
  const bool dead = n0_raw >= N;
  const int n0 = dead ? 0 : n0_raw;

  // ---- phase 1: aggregate (in-register A-frag build) ----
  const int r = base + n0 + col;
  const int ps = row_ptr[r], pe = row_ptr[r + 1];
  float acc0[8], acc1[8];
#pragma unroll
  for (int j = 0; j < 8; ++j) { acc0[j] = 0.0f; acc1[j] = 0.0f; }
  float wsum = 0.0f;
  int p = ps;
  for (; p + 4 <= pe; p += 4) {  // x4 unroll: 8 gathers in flight per lane
    unsigned av[4];
#pragma unroll
    for (int j = 0; j < 4; ++j) av[j] = adj[p + j];
    bf16x8 m0[4], m1[4];
#pragma unroll
    for (int j = 0; j < 4; ++j) {
      const unsigned short* m = MSGsrc + (size_t)(av[j] >> 14) * 64 + quad * 8;
      m0[j] = *(const bf16x8*)m;
      m1[j] = *(const bf16x8*)(m + 32);
    }
#pragma unroll
    for (int j = 0; j < 4; ++j) {
      const float w = (float)(av[j] & 16383u) * WQ_INV;
      wsum += w;
      const unsigned* u0 = (const unsigned*)&m0[j];
      const unsigned* u1 = (const unsigned*)&m1[j];
#pragma unroll
      for (int q = 0; q < 4; ++q) {
        acc0[2 * q] = fmaf(__uint_as_float(u0[q] << 16), w, acc0[2 * q]);
        acc0[2 * q + 1] = fmaf(__uint_as_float(u0[q] & 0xffff0000u), w, acc0[2 * q + 1]);
        acc1[2 * q] = fmaf(__uint_as_float(u1[q] << 16), w, acc1[2 * q]);
        acc1[2 * q + 1] = fmaf(__uint_as_float(u1[q] & 0xffff0000u), w, acc1[2 * q + 1]);
      }
    }
  }
  for (; p + 2 <= pe; p += 2) {  // x2 tail
    const unsigned avA = adj[p], avB = adj[p + 1];
    const unsigned short* mA = MSGsrc + (size_t)(avA >> 14) * 64 + quad * 8;
    const unsigned short* mB = MSGsrc + (size_t)(avB >> 14) * 64 + quad * 8;
    const bf16x8 mA0 = *(const bf16x8*)mA;
    const bf16x8 mA1 = *(const bf16x8*)(mA + 32);
    const bf16x8 mB0 = *(const bf16x8*)mB;
    const bf16x8 mB1v = *(const bf16x8*)(mB + 32);
    const float wA = (float)(avA & 16383u) * WQ_INV;
    const float wB = (float)(avB & 16383u) * WQ_INV;
    wsum += wA;
    wsum += wB;
    const unsigned* uA0 = (const unsigned*)&mA0;
    const unsigned* uA1 = (const unsigned*)&mA1;
    const unsigned* uB0 = (const unsigned*)&mB0;
    const unsigned* uB1v = (const unsigned*)&mB1v;
#pragma unroll
    for (int q = 0; q < 4; ++q) {
      acc0[2 * q] = fmaf(__uint_as_float(uA0[q] << 16), wA, acc0[2 * q]);
      acc0[2 * q + 1] = fmaf(__uint_as_float(uA0[q] & 0xffff0000u), wA, acc0[2 * q + 1]);
      acc1[2 * q] = fmaf(__uint_as_float(uA1[q] << 16), wA, acc1[2 * q]);
      acc1[2 * q + 1] = fmaf(__uint_as_float(uA1[q] & 0xffff0000u), wA, acc1[2 * q + 1]);
      acc0[2 * q] = fmaf(__uint_as_float(uB0[q] << 16), wB, acc0[2 * q]);
      acc0[2 * q + 1] = fmaf(__uint_as_float(uB0[q] & 0xffff0000u), wB, acc0[2 * q + 1]);
      acc1[2 * q] = fmaf(__uint_as_float(uB1v[q] << 16), wB, acc1[2 * q]);
      acc1[2 * q + 1] = fmaf(__uint_as_float(uB1v[q] & 0xffff0000u), wB, acc1[2 * q + 1]);
    }
  }
  if (p < pe) {
    const unsigned av = adj[p];
    const unsigned short* m = MSGsrc + (size_t)(av >> 14) * 64 + quad * 8;
    const bf16x8 m0 = *(const bf16x8*)m;
    const bf16x8 m1 = *(const bf16x8*)(m + 32);
    const float w = (float)(av & 16383u) * WQ_INV;
    wsum += w;
    const unsigned* u0 = (const unsigned*)&m0;
    const unsigned* u1 = (const unsigned*)&m1;
#pragma unroll
    for (int q = 0; q < 4; ++q) {
      acc0[2 * q] = fmaf(__uint_as_float(u0[q] << 16), w, acc0[2 * q]);
      acc0[2 * q + 1] = fmaf(__uint_as_float(u0[q] & 0xffff0000u), w, acc0[2 * q + 1]);
      acc1[2 * q] = fmaf(__uint_as_float(u1[q] << 16), w, acc1[2 * q]);
      acc1[2 * q + 1] = fmaf(__uint_as_float(u1[q] & 0xffff0000u), w, acc1[2 * q + 1]);
    }
  }
  const float di = 1.0f / fmaxf(wsum, 1.0f);
  bf16x8 aA0, aA1;
#pragma unroll
  for (int j = 0; j < 8; ++j) {
    aA0[j] = (short)f2bf(acc0[j] * di);
    aA1[j] = (short)f2bf(acc1[j] * di);
  }

  // ---- phase 2: gate + upd1 (MFMA) ----
  const unsigned short* nrow = NODEb + (size_t)(n0 + col) * 64 + quad * 8;
  const bf16x8 aN0 = *(const bf16x8*)nrow;
  const bf16x8 aN1 = *(const bf16x8*)(nrow + 32);
  const bf16x8* gW = (const bf16x8*)gWp;
  const bf16x8* uW1 = (const bf16x8*)uW1p;
  const bf16x8* uW2 = (const bf16x8*)uW2p;

  f32x4 g[4], u[4];
#pragma unroll
  for (int t = 0; t < 4; ++t) {
    const float bg = gB[col + 16 * t], bu = uB1[col + 16 * t];
    g[t] = f32x4{bg, bg, bg, bg};
    u[t] = f32x4{bu, bu, bu, bu};
  }
#pragma unroll
  for (int t = 0; t < 4; ++t) {
    g[t] = __builtin_amdgcn_mfma_f32_16x16x32_bf16(aA0, gW[t * 64 + l], g[t], 0, 0, 0);
    g[t] = __builtin_amdgcn_mfma_f32_16x16x32_bf16(aA1, gW[(4 + t) * 64 + l], g[t], 0, 0, 0);
    g[t] = __builtin_amdgcn_mfma_f32_16x16x32_bf16(aN0, gW[(8 + t) * 64 + l], g[t], 0, 0, 0);
    g[t] = __builtin_amdgcn_mfma_f32_16x16x32_bf16(aN1, gW[(12 + t) * 64 + l], g[t], 0, 0, 0);
    u[t] = __builtin_amdgcn_mfma_f32_16x16x32_bf16(aA0, uW1[t * 64 + l], u[t], 0, 0, 0);
    u[t] = __builtin_amdgcn_mfma_f32_16x16x32_bf16(aA1, uW1[(4 + t) * 64 + l], u[t], 0, 0, 0);
    u[t] = __builtin_amdgcn_mfma_f32_16x16x32_bf16(aN0, uW1[(8 + t) * 64 + l], u[t], 0, 0, 0);
    u[t] = __builtin_amdgcn_mfma_f32_16x16x32_bf16(aN1, uW1[(12 + t) * 64 + l], u[t], 0, 0, 0);
  }
#pragma unroll
  for (int t = 0; t < 4; ++t)
#pragma unroll
    for (int r2 = 0; r2 < 4; ++r2) g[t][r2] = sigmoid_f(g[t][r2]);

  unsigned short* ld = lds[wave];
#pragma unroll
  for (int t = 0; t < 4; ++t)
#pragma unroll
    for (int r2 = 0; r2 < 4; ++r2)
      ld[(quad * 4 + r2) * 72 + col + 16 * t] = f2bf(fmaxf(u[t][r2], 0.0f));
  // no barrier: per-wave LDS slice, in-order ds ops within the wave
  const bf16x8 h0 = *(const bf16x8*)&ld[col * 72 + quad * 8];
  const bf16x8 h1 = *(const bf16x8*)&ld[col * 72 + 32 + quad * 8];
  f32x4 o[4];
#pragma unroll
  for (int t = 0; t < 4; ++t) {
    const float b = uB2[col + 16 * t];
    o[t] = f32x4{b, b, b, b};
  }
#pragma unroll
  for (int t = 0; t < 4; ++t) {
    o[t] = __builtin_amdgcn_mfma_f32_16x16x32_bf16(h0, uW2[t * 64 + l], o[t], 0, 0, 0);
    o[t] = __builtin_amdgcn_mfma_f32_16x16x32_bf16(h1, uW2[(4 + t) * 64 + l], o[t], 0, 0, 0);
  }
  // gate mix (bf16 node carry, C-layout gather) + LayerNorm
  float om[4][4];
#pragma unroll
  for (int t = 0; t < 4; ++t)
#pragma unroll
    for (int r2 = 0; r2 < 4; ++r2) {
      const float nd =
          bf2f(NODEb[(size_t)(n0 + quad * 4 + r2) * 64 + col + 16 * t]);
      om[t][r2] = fmaf(g[t][r2], o[t][r2] - nd, nd);
    }
  float outv[4][4];
#pragma unroll
  for (int r2 = 0; r2 < 4; ++r2) {
    float s1 = (om[0][r2] + om[1][r2]) + (om[2][r2] + om[3][r2]);
    float s2 = fmaf(om[0][r2], om[0][r2], fmaf(om[1][r2], om[1][r2],
                fmaf(om[2][r2], om[2][r2], om[3][r2] * om[3][r2])));
#pragma unroll
    for (int off = 1; off < 16; off <<= 1) {
      s1 += __shfl_xor(s1, off, 64);
      s2 += __shfl_xor(s2, off, 64);
    }
    const float m = s1 * (1.0f / 64.0f);
    const float var = s2 * (1.0f / 64.0f) - m * m;
    const float rr = rsqrtf(var + 1e-3f);
#pragma unroll
    for (int t = 0; t < 4; ++t)
      outv[t][r2] = fmaf((om[t][r2] - m) * rr, LNG[col + 16 * t], LNB[col + 16 * t]);
  }
  if (OUTf != nullptr && !dead) {
#pragma unroll
    for (int t = 0; t < 4; ++t)
#pragma unroll
      for (int r2 = 0; r2 < 4; ++r2)
        OUTf[(size_t)(n0 + quad * 4 + r2) * 64 + col + 16 * t] = outv[t][r2];
  }
  // no barrier (WAR on ld ordered by per-wave in-order ds ops)
#pragma unroll
  for (int t = 0; t < 4; ++t)
#pragma unroll
    for (int r2 = 0; r2 < 4; ++r2)
      ld[(quad * 4 + r2) * 72 + col + 16 * t] = f2bf(outv[t][r2]);
  if (OUTb != nullptr && !dead) {
#pragma unroll
    for (int cc = 0; cc < 2; ++cc) {
      const bf16x8 v = *(const bf16x8*)&ld[col * 72 + (quad * 2 + cc) * 8];
      *(bf16x8*)(OUTb + (size_t)(n0 + col) * 64 + (quad * 2 + cc) * 8) = v;
    }
  }

  if constexpr (WITH_MSG) {
    // ---- phase 3: next layer's message MLP on the just-updated rows ----
    const bf16x8 x0 = *(const bf16x8*)&ld[col * 72 + quad * 8];
    const bf16x8 x1 = *(const bf16x8*)&ld[col * 72 + 32 + quad * 8];
    const bf16x8* W1p = (const bf16x8*)mWp;
    const bf16x8* W2p = (const bf16x8*)(mWp + 4096);
    f32x4 macc[4];
#pragma unroll
    for (int t = 0; t < 4; ++t) {
      const float b = mB1[col + 16 * t];
      macc[t] = f32x4{b, b, b, b};
    }
#pragma unroll
    for (int t = 0; t < 4; ++t) {
      macc[t] = __builtin_amdgcn_mfma_f32_16x16x32_bf16(x0, W1p[t * 64 + l], macc[t], 0, 0, 0);
      macc[t] = __builtin_amdgcn_mfma_f32_16x16x32_bf16(x1, W1p[(4 + t) * 64 + l], macc[t], 0, 0, 0);
    }
#pragma unroll
    for (int t = 0; t < 4; ++t)
#pragma unroll
      for (int r2 = 0; r2 < 4; ++r2)
        ld[(quad * 4 + r2) * 72 + col + 16 * t] = f2bf(fmaxf(macc[t][r2], 0.0f));
    const bf16x8 mh0 = *(const bf16x8*)&ld[col * 72 + quad * 8];
    const bf16x8 mh1 = *(const bf16x8*)&ld[col * 72 + 32 + quad * 8];
    f32x4 mo[4];
#pragma unroll
    for (int t = 0; t < 4; ++t) {
      const float b = mB2[col + 16 * t];
      mo[t] = f32x4{b, b, b, b};
    }
#pragma unroll
    for (int t = 0; t < 4; ++t) {
      mo[t] = __builtin_amdgcn_mfma_f32_16x16x32_bf16(mh0, W2p[t * 64 + l], mo[t], 0, 0, 0);
      mo[t] = __builtin_amdgcn_mfma_f32_16x16x32_bf16(mh1, W2p[(4 + t) * 64 + l], mo[t], 0, 0, 0);
    }
#pragma unroll
    for (int t = 0; t < 4; ++t)
#pragma unroll
      for (int r2 = 0; r2 < 4; ++r2)
        ld[(quad * 4 + r2) * 72 + col + 16 * t] = f2bf(mo[t][r2]);
    if (!dead) {
#pragma unroll
      for (int cc = 0; cc < 2; ++cc) {
        const bf16x8 v = *(const bf16x8*)&ld[col * 72 + (quad * 2 + cc) * 8];
        *(bf16x8*)(MSGdst + (size_t)(n0 + col) * 64 + (quad * 2 + cc) * 8) = v;
      }
    }
  }
}

// ===== edge weight + degree count w/ captured slot index (atomic return) =====
DEVINL void edgew_body(const int* __restrict__ S, const int* __restrict__ D,
                       const float* __restrict__ EFX,
                       const unsigned short* __restrict__ PA,
                       const unsigned short* __restrict__ PB,
                       const float* __restrict__ W1C,
                       const float* __restrict__ W2, const float* __restrict__ B2,
                       unsigned long long* __restrict__ stagedD,
                       unsigned long long* __restrict__ stagedS,
                       int* __restrict__ counts, int baseD, int baseS, int E,
                       int bid, int nb) {
  const int l = threadIdx.x & 63;
  const int g = l >> 3, c = l & 7;
  float wc[8][8];
#pragma unroll
  for (int i = 0; i < 8; ++i) {
    const float4 v0 = *(const float4*)(W1C + i * 64 + c * 8);
    const float4 v1 = *(const float4*)(W1C + i * 64 + c * 8 + 4);
    wc[i][0] = v0.x; wc[i][1] = v0.y; wc[i][2] = v0.z; wc[i][3] = v0.w;
    wc[i][4] = v1.x; wc[i][5] = v1.y; wc[i][6] = v1.z; wc[i][7] = v1.w;
  }
  float w2c[8];
  {
    const float4 a0 = *(const float4*)(W2 + c * 8);
    const float4 a1 = *(const float4*)(W2 + c * 8 + 4);
    w2c[0] = a0.x; w2c[1] = a0.y; w2c[2] = a0.z; w2c[3] = a0.w;
    w2c[4] = a1.x; w2c[5] = a1.y; w2c[6] = a1.z; w2c[7] = a1.w;
  }
  const float b2 = B2[0];
  const int wave_id = bid * 4 + (threadIdx.x >> 6);
  const int nwaves = nb * 4;
  for (int t0 = wave_id * 8; t0 < E; t0 += nwaves * 8) {
    const int e = t0 + g;
    const bool ok = e < E;
    const int ee = ok ? e : E - 1;
    const int s = __builtin_nontemporal_load(S + ee);
    const int d = __builtin_nontemporal_load(D + ee);
    // issue slot-index atomics EARLY; latency hides under the MLP below
    int kd = 0, ks = 0;
    const int rd = baseD + d, rs = baseS + s;
    if (ok && c == 0) {
      kd = atomicAdd(&counts[rd], 1);
      ks = atomicAdd(&counts[rs], 1);
    }
    const bf16x8 pa = *(const bf16x8*)(PA + (size_t)s * 64 + c * 8);
    const bf16x8 pb = *(const bf16x8*)(PB + (size_t)d * 64 + c * 8);
    const f32x4 ef0 =
        __builtin_nontemporal_load((const f32x4*)(EFX + (size_t)ee * 8));
    const f32x4 ef1 =
        __builtin_nontemporal_load((const f32x4*)(EFX + (size_t)ee * 8 + 4));
    const unsigned* pau = (const unsigned*)&pa;
    const unsigned* pbu = (const unsigned*)&pb;
    float h[8];
#pragma unroll
    for (int q = 0; q < 4; ++q) {
      h[2 * q] = __uint_as_float(pau[q] << 16) + __uint_as_float(pbu[q] << 16);
      h[2 * q + 1] = __uint_as_float(pau[q] & 0xffff0000u) +
                     __uint_as_float(pbu[q] & 0xffff0000u);
    }
    const float ef[8] = {ef0[0], ef0[1], ef0[2], ef0[3],
                         ef1[0], ef1[1], ef1[2], ef1[3]};
#pragma unroll
    for (int i = 0; i < 8; ++i)
#pragma unroll
      for (int j = 0; j < 8; ++j) h[j] = fmaf(ef[i], wc[i][j], h[j]);
    float t = 0.0f;
#pragma unroll
    for (int j = 0; j < 8; ++j) t = fmaf(fmaxf(h[j], 0.0f), w2c[j], t);
#pragma unroll
    for (int off = 1; off < 8; off <<= 1) t += __shfl_xor(t, off, 64);
    if (ok && c == 0) {
      const float w = sigmoid_f(t + b2);
      const unsigned w14 = (unsigned)(w * WQ_SCALE + 0.5f);
      stagedD[e] =
          (unsigned long long)((unsigned)rd | ((unsigned)kd << 19)) |
          ((unsigned long long)(((unsigned)s << 14) | w14) << 32);
      stagedS[e] =
          (unsigned long long)((unsigned)rs | ((unsigned)ks << 19)) |
          ((unsigned long long)(((unsigned)d << 14) | w14) << 32);
    }
  }
}

// merged: VC (blocks 0..NB_EVC-1) and VK (rest) in ONE dispatch so the two
// independent edge sweeps co-schedule (VK fills VC's tail instead of waiting).
__global__ void __launch_bounds__(256) edgew2_k(
    const int* __restrict__ S0, const int* __restrict__ D0,
    const float* __restrict__ EFX0, const unsigned short* __restrict__ PA0,
    const unsigned short* __restrict__ PB0, const float* __restrict__ W1C0,
    const float* __restrict__ W20, const float* __restrict__ B20,
    unsigned long long* __restrict__ sD0, unsigned long long* __restrict__ sS0,
    const int* __restrict__ S1, const int* __restrict__ D1,
    const float* __restrict__ EFX1, const unsigned short* __restrict__ PA1,
    const unsigned short* __restrict__ PB1, const float* __restrict__ W1C1,
    const float* __restrict__ W21, const float* __restrict__ B21,
    unsigned long long* __restrict__ sD1, unsigned long long* __restrict__ sS1,
    int* __restrict__ counts) {
  if (blockIdx.x < NB_EVC)
    edgew_body(S0, D0, EFX0, PA0, PB0, W1C0, W20, B20, sD0, sS0, counts,
               0, NC, EVC, blockIdx.x, NB_EVC);
  else
    edgew_body(S1, D1, EFX1, PA1, PB1, W1C1, W21, B21, sD1, sS1, counts,
               NC + NV, NC + NV + NK, EVK, blockIdx.x - NB_EVC, NB_EVK);
}

// ==== atomic-free CSR fill: bin=blockIdx&7 pins a row range to one XCD =====
__global__ void __launch_bounds__(256) fill_staged_k(
    const unsigned long long* __restrict__ staged,
    const int* __restrict__ row_ptr, unsigned* __restrict__ adj) {
  const int bin = blockIdx.x & 7;
  const int blk = blockIdx.x >> 3;
  const int nblk = gridDim.x >> 3;
  const int lo = (bin == 0) ? 0 : c_bin_hi[bin - 1];
  const int hi = c_bin_hi[bin];
  const int slo = c_seg_lo[bin], shi = c_seg_hi[bin];
  for (int i = slo + blk * 256 + threadIdx.x; i < shi; i += nblk * 256) {
    const unsigned long long v = __builtin_nontemporal_load(staged + i);
    const int row = (int)(v & 0x7ffffull);
    if (row >= lo && row < hi) {
      const int k = (int)((v >> 19) & 0x1fffull);
      adj[row_ptr[row] + k] = (unsigned)(v >> 32);
    }
  }
}

__global__ void __launch_bounds__(256) scan1_k(const int* __restrict__ in,
                                               int* __restrict__ bsum) {
  __shared__ int sd[256];
  const int t = threadIdx.x;
  const int base = blockIdx.x * SCAN_CHUNK + t * 8;
  int s = 0;
#pragma unroll
  for (int i = 0; i < 8; ++i) {
    const int idx = base + i;
    s += (idx < R_TOT) ? in[idx] : 0;
  }
  sd[t] = s;
  __syncthreads();
  for (int off = 128; off > 0; off >>= 1) {
    if (t < off) sd[t] += sd[t + off];
    __syncthreads();
  }
  if (t == 0) bsum[blockIdx.x] = sd[0];
}

__global__ void __launch_bounds__(256) scan2_k(int* __restrict__ bsum,
                                               int* __restrict__ row_ptr) {
  __shared__ int sd[256];
  const int t = threadIdx.x;
  const int v = (t < SCAN_NB) ? bsum[t] : 0;
  sd[t] = v;
  __syncthreads();
  for (int off = 1; off < 256; off <<= 1) {
    const int add = (t >= off) ? sd[t - off] : 0;
    __syncthreads();
    sd[t] += add;
    __syncthreads();
  }
  if (t < SCAN_NB) bsum[t] = sd[t] - v;
  if (t == 255) row_ptr[R_TOT] = sd[255];
}

__global__ void __launch_bounds__(256) scan3_k(const int* __restrict__ in,
                                               const int* __restrict__ bsum,
                                               int* __restrict__ out) {
  __shared__ int sd[256];
  const int t = threadIdx.x;
  const int base = blockIdx.x * SCAN_CHUNK + t * 8;
  int loc[8];
  int s = 0;
#pragma unroll
  for (int i = 0; i < 8; ++i) {
    loc[i] = s;
    const int idx = base + i;
    s += (idx < R_TOT) ? in[idx] : 0;
  }
  sd[t] = s;
  __syncthreads();
  const int v = s;
  for (int off = 1; off < 256; off <<= 1) {
    const int add = (t >= off) ? sd[t - off] : 0;
    __syncthreads();
    sd[t] += add;
    __syncthreads();
  }
  const int off0 = bsum[blockIdx.x] + (sd[t] - v);
#pragma unroll
  for (int i = 0; i < 8; ++i) {
    const int idx = base + i;
    if (idx < R_TOT) out[idx] = off0 + loc[i];
  }
}

}  // namespace

extern "C" void kernel_launch(void* const* d_in, const int* in_sizes, int n_in,
                              void* d_out, int out_size, void* d_ws, size_t ws_size,
                              hipStream_t stream) {
  (void)in_sizes; (void)n_in; (void)out_size; (void)ws_size;

  const float* variable_features   = (const float*)d_in[0];
  const float* constraint_features = (const float*)d_in[1];
  const float* cut_features        = (const float*)d_in[2];
  const float* vc_ef = (const float*)d_in[3];
  const float* vk_ef = (const float*)d_in[4];
  const int* vc_edges = (const int*)d_in[5];
  const int* vk_edges = (const int*)d_in[6];
  const int *vc_s = vc_edges, *vc_d = vc_edges + EVC;
  const int *vk_s = vk_edges, *vk_d = vk_edges + EVK;
  const float* var_w1  = (const float*)d_in[7];
  const float* var_b1  = (const float*)d_in[8];
  const float* var_w2  = (const float*)d_in[9];
  const float* var_b2  = (const float*)d_in[10];
  const float* cons_w1 = (const float*)d_in[11];
  const float* cons_b1 = (const float*)d_in[12];
  const float* cons_w2 = (const float*)d_in[13];
  const float* cons_b2 = (const float*)d_in[14];
  const float* cut_w1  = (const float*)d_in[15];
  const float* cut_b1  = (const float*)d_in[16];
  const float* cut_w2  = (const float*)d_in[17];
  const float* cut_b2  = (const float*)d_in[18];
  const float* ewvc_w1 = (const float*)d_in[19];
  const float* ewvc_b1 = (const float*)d_in[20];
  const float* ewvc_w2 = (const float*)d_in[21];
  const float* ewvc_b2 = (const float*)d_in[22];
  const float* ewvk_w1 = (const float*)d_in[23];
  const float* ewvk_b1 = (const float*)d_in[24];
  const float* ewvk_w2 = (const float*)d_in[25];
  const float* ewvk_b2 = (const float*)d_in[26];
  const float* mp_msg_w1 = (const float*)d_in[27];
  const float* mp_msg_b1 = (const float*)d_in[28];
  const float* mp_msg_w2 = (const float*)d_in[29];
  const float* mp_msg_b2 = (const float*)d_in[30];
  const float* mp_gate_w = (const float*)d_in[31];
  const float* mp_gate_b = (const float*)d_in[32];
  const float* mp_upd_w1 = (const float*)d_in[33];
  const float* mp_upd_b1 = (const float*)d_in[34];
  const float* mp_upd_w2 = (const float*)d_in[35];
  const float* mp_upd_b2 = (const float*)d_in[36];
  const float* mp_ln_g   = (const float*)d_in[37];
  const float* mp_ln_b   = (const float*)d_in[38];

  // ---- workspace carve ----
  char* wp = (char*)d_ws;
  auto take = [&](size_t nbytes) {
    char* p = wp;
    wp += (nbytes + 255) & ~(size_t)255;
    return p;
  };
  unsigned short* h_var_b  = (unsigned short*)take((size_t)NV * 64 * 2);
  unsigned short* h_cons_b = (unsigned short*)take((size_t)NC * 64 * 2);
  unsigned short* h_cut_b  = (unsigned short*)take((size_t)NK * 64 * 2);
  unsigned short* msg_ping = (unsigned short*)take((size_t)NV * 64 * 2);
  unsigned short* msg_pong = (unsigned short*)take((size_t)NV * 64 * 2);
  unsigned short* pa = (unsigned short*)take((size_t)NV * 64 * 2);
  unsigned short* pb = (unsigned short*)take((size_t)NC * 64 * 2);
  unsigned short* qa = (unsigned short*)take((size_t)NV * 64 * 2);
  unsigned short* qb = (unsigned short*)take((size_t)NK * 64 * 2);
  unsigned short* packW = (unsigned short*)take((size_t)15 * PACK_PER_LAYER * 2);
  unsigned short* packE = (unsigned short*)take((size_t)PE_TOTAL * 2);
  int* row_ptr = (int*)take((size_t)(R_TOT + 1) * 4);
  int* counts  = (int*)take((size_t)R_TOT * 4);
  int* bsum    = (int*)take(256 * 4);
  unsigned* adj = (unsigned*)take((size_t)(2 * EVC + 2 * EVK) * 4);

  // ---- time-sliced alias (no extra workspace) ----
  // staged pairs (16MB, live: edgew -> fill_staged) alias msg ping+pong
  // (25.6MB, first written by msg_mfma_k long after fill completes).
  unsigned long long* staged = (unsigned long long*)msg_ping;

  // ---- init counts (filled during edgew) ----
  hipMemsetAsync(counts, 0, (size_t)R_TOT * 4, stream);

  // ---- pack weights (MP layers + embeddings/edge-weight mats) ----
  pack_k<<<15, 256, 0, stream>>>(mp_msg_w1, mp_msg_w2, mp_gate_w, mp_upd_w1,
                                 mp_upd_w2, packW);
  pack_emb_k<<<10, 256, 0, stream>>>(var_w1, var_w2, cons_w1, cons_w2, cut_w1,
                                     cut_w2, ewvc_w1, ewvk_w1, packE);

  // ---- embeddings (MFMA, bf16 out; var|cons|cut merged into 1 dispatch) ----
  emb3_k<<<NB_VAR + NB_CONS + NB_CUT, 256, 0, stream>>>(
      variable_features, constraint_features, cut_features, packE,
      var_b1, var_b2, cons_b1, cons_b2, cut_b1, cut_b2,
      h_var_b, h_cons_b, h_cut_b);

  // ---- edge-weight per-node terms (merged into 1 dispatch) ----
  gemv3_k<<<NB_VAR + NB_CONS + NB_CUT, 256, 0, stream>>>(
      h_var_b, h_cons_b, h_cut_b, packE, ewvc_b1, ewvk_b1, pa, qa, pb, qb);

  // ---- edge weights + degree counts, VC+VK merged (co-scheduled) ----
  edgew2_k<<<NB_EVC + NB_EVK, 256, 0, stream>>>(
      vc_s, vc_d, vc_ef, pa, pb, ewvc_w1 + 128 * 64, ewvc_w2, ewvc_b2,
      staged, staged + EVC,
      vk_s, vk_d, vk_ef, qa, qb, ewvk_w1 + 128 * 64, ewvk_w2, ewvk_b2,
      staged + 2 * EVC, staged + 2 * EVC + EVK, counts);

  // ---- CSR scan + atomic-free XCD-local fill (degi fused into passes) ----
  scan1_k<<<SCAN_NB, 256, 0, stream>>>(counts, bsum);
  scan2_k<<<1, 256, 0, stream>>>(bsum, row_ptr);
  scan3_k<<<SCAN_NB, 256, 0, stream>>>(counts, bsum, row_ptr);
  fill_staged_k<<<8 * 192, 256, 0, stream>>>(staged, row_ptr, adj);

  // ---- 15 fully-fused passes (agg + upd + next msg), msg ping-pong ----
  unsigned short* nodeb_t[4] = {h_cons_b, h_var_b, h_cut_b, h_var_b};
  const int Nd_t[4] = {NC, NV, NK, NV};
  const int base_t[4] = {0, NC, NC + NV, NC + NV + NK};

  // msg(0): over h_var with layer-0 msg weights -> ping
  msg_mfma_k<<<(NV + 63) / 64, 256, 0, stream>>>(
      h_var_b, packW, mp_msg_b1, mp_msg_b2, msg_ping, NV);

  for (int i = 0; i < 15; ++i) {
    const int d = i & 3;
    const int Nd = Nd_t[d], base = base_t[d];
    const unsigned short* Wl = packW + (size_t)i * PACK_PER_LAYER;
    const unsigned short* src = (i % 2 == 0) ? msg_ping : msg_pong;
    unsigned short* dst = (i % 2 == 0) ? msg_pong : msg_ping;

    if (i < 14) {
      const unsigned short* Wn = packW + (size_t)(i + 1) * PACK_PER_LAYER;
      pass_mfma_k<1><<<(Nd + 63) / 64, 256, 0, stream>>>(
          row_ptr, adj, src, nodeb_t[d], Wl + 8192, Wl + 16384,
          Wl + 24576, mp_gate_b + (size_t)i * 64, mp_upd_b1 + (size_t)i * 64,
          mp_upd_b2 + (size_t)i * 64, mp_ln_g + (size_t)i * 64,
          mp_ln_b + (size_t)i * 64, Wn, mp_msg_b1 + (size_t)(i + 1) * 64,
          mp_msg_b2 + (size_t)(i + 1) * 64, nullptr, nodeb_t[d], dst, base, Nd);
    } else {
      pass_mfma_k<0><<<(Nd + 63) / 64, 256, 0, stream>>>(
          row_ptr, adj, src, nodeb_t[d], Wl + 8192, Wl + 16384,
          Wl + 24576, mp_gate_b + (size_t)i * 64, mp_upd_b1 + (size_t)i * 64,
          mp_upd_b2 + (size_t)i * 64, mp_ln_g + (size_t)i * 64,
          mp_ln_b + (size_t)i * 64, nullptr, nullptr, nullptr,
          (float*)d_out, nullptr, nullptr, base, Nd);
    }
  }
}